// Round 14
// baseline (745.522 us; speedup 1.0000x reference)
//
#include <hip/hip_runtime.h>
#include <stdint.h>

typedef unsigned short U16;
typedef float f32x4 __attribute__((ext_vector_type(4)));
typedef __bf16 bf16x8 __attribute__((ext_vector_type(8)));

static __device__ __forceinline__ U16 f2bf(float x) {
  union { float f; unsigned u; } v; v.f = x;
  unsigned r = v.u + 0x7FFFu + ((v.u >> 16) & 1u);
  return (U16)(r >> 16);
}
static __device__ __forceinline__ float bf2f(U16 h) {
  union { unsigned u; float f; } v; v.u = ((unsigned)h) << 16;
  return v.f;
}

static __device__ __forceinline__ void gload_lds16(const void* g, void* l) {
  __builtin_amdgcn_global_load_lds(
      (const __attribute__((address_space(1))) void*)g,
      (__attribute__((address_space(3))) void*)l, 16, 0, 0);
}

#define SBAR() __builtin_amdgcn_sched_barrier(0)

// ---------------- hidden (fp32) -> bf16 -------------------------------------
__global__ __launch_bounds__(256) void k_convert(const float* __restrict__ src,
                                                 U16* __restrict__ dst, long n) {
  long base = ((long)blockIdx.x * 256 + threadIdx.x) * 8;
  if (base >= n) return;
  const float4* s = (const float4*)(src + base);
  float4 a = s[0], b = s[1];
  U16 o[8] = { f2bf(a.x), f2bf(a.y), f2bf(a.z), f2bf(a.w),
               f2bf(b.x), f2bf(b.y), f2bf(b.z), f2bf(b.w) };
  *(uint4*)(dst + base) = *(const uint4*)o;
}

// ---------------- W[K][N] (fp32) -> Wt[N][K] bf16 ----------------------------
__global__ __launch_bounds__(256) void k_transpose(const float* __restrict__ src,
                                                   U16* __restrict__ dst,
                                                   int K, int N) {
  __shared__ U16 tile[32][33];
  int n0 = blockIdx.x * 32, k0 = blockIdx.y * 32;
  int tx = threadIdx.x & 31, ty = threadIdx.x >> 5;
#pragma unroll
  for (int r = 0; r < 4; ++r) {
    int k = k0 + ty + r * 8;
    tile[ty + r * 8][tx] = f2bf(src[(long)k * N + n0 + tx]);
  }
  __syncthreads();
#pragma unroll
  for (int r = 0; r < 4; ++r) {
    int n = n0 + ty + r * 8;
    dst[(long)n * K + k0 + tx] = tile[tx][ty + r * 8];
  }
}

// ---- V section of QKV -> VT tiled [bk][sTile=64][d=256][s32=32] bf16 -------
__global__ __launch_bounds__(256) void k_vtrans(const U16* __restrict__ QKV,
                                                U16* __restrict__ VT) {
  __shared__ U16 tile[32][33];
  int s0 = blockIdx.x * 32, d0 = blockIdx.y * 32, bk = blockIdx.z;
  int b = bk >> 3, kvh = bk & 7;
  int tx = threadIdx.x & 31, ty = threadIdx.x >> 5;
  const U16* src = QKV + (long)(b * 2048) * 8192 + 6144 + kvh * 256;
#pragma unroll
  for (int r = 0; r < 4; ++r) {
    int s = s0 + ty + r * 8;
    tile[ty + r * 8][tx] = src[(long)s * 8192 + d0 + tx];
  }
  __syncthreads();
  long tbase = ((long)bk * 64 + (s0 >> 5)) * 8192;
#pragma unroll
  for (int r = 0; r < 4; ++r) {
    int d = d0 + ty + r * 8;
    VT[tbase + d * 32 + tx] = tile[tx][ty + r * 8];
  }
}

// ---------------- RoPE tables (fp32) ----------------------------------------
__global__ __launch_bounds__(256) void k_rope_tables(float* __restrict__ cosT,
                                                     float* __restrict__ sinT) {
  int i = blockIdx.x * 256 + threadIdx.x;
  int s = i >> 7, d = i & 127;
  float freq = expf(-9.210340371976184f * (float)d / 128.0f);
  float ang = (float)s * freq;
  cosT[i] = cosf(ang);
  sinT[i] = sinf(ang);
}

// ---------------- GEMM v7: 256x256, BK=64, 8-PHASE, lane-ordered granules ---
// Granule g (16B) of each 1KB sub-block now holds the fragment data of
// READ-LANE g: row (g&15), k-chunk (g>>4)*8. Reads are lofs = lane*16 ->
// every 16-lane group reads 256 contiguous bytes (all 32 banks x2, free).
// Staging source permuted to match; union of addresses per instruction
// unchanged -> identical coalescing. Output bitwise identical.
template <int EPI>
__global__ __launch_bounds__(512, 1) void k_gemm8(const U16* __restrict__ A,
                                                  const U16* __restrict__ Bt,
                                                  void* __restrict__ Cv,
                                                  const float* __restrict__ cosT,
                                                  const float* __restrict__ sinT,
                                                  int M, int N, int K) {
  __shared__ __align__(16) U16 Asl[2][2][128 * 64];
  __shared__ __align__(16) U16 Bsl[2][2][128 * 64];
  int nwg = gridDim.x * gridDim.y;
  int flat = blockIdx.y * gridDim.x + blockIdx.x;
  int cpx = nwg >> 3;
  int swz = (flat & 7) * cpx + (flat >> 3);
  int bx = swz % gridDim.x, by = swz / gridDim.x;
  int t = threadIdx.x, lane = t & 63, w = t >> 6;
  int m0 = by * 256, n0 = bx * 256;
  int wm = w >> 2, wn = w & 3;
  int l15 = lane & 15, l4 = lane >> 4;
  int lofs = lane * 16;                      // lane-ordered granule read

  f32x4 acc[8][4] = {};
  int T = K >> 6;

  // staging source: granule g=lane holds row (lane&15), k-chunk (lane>>4)*8
  int sr = lane & 15, sc4 = (lane >> 4) * 8;
  int fA0 = (w >> 1) * 16 + sr, kA0 = (w & 1) * 32 + sc4;
  int fA1 = ((8 + w) >> 1) * 16 + sr, kA1 = ((8 + w) & 1) * 32 + sc4;
  const U16* aj0 = A + (long)(m0 + fA0) * K + kA0;
  const U16* aj1 = A + (long)(m0 + fA1) * K + kA1;
  const U16* bj0 = Bt + (long)(n0 + fA0) * K + kA0;
  const U16* bj1 = Bt + (long)(n0 + fA1) * K + kA1;

  auto stageH = [&](int op, int kt, int h) {
    int buf = kt & 1;
    int ktc = (kt < T) ? kt : 0;
    long off = (long)ktc * 64 + (long)h * 128 * K;
    if (op == 0) {
      gload_lds16(aj0 + off, (char*)&Asl[buf][h][0] + w * 1024);
      gload_lds16(aj1 + off, (char*)&Asl[buf][h][0] + 8192 + w * 1024);
    } else {
      gload_lds16(bj0 + off, (char*)&Bsl[buf][h][0] + w * 1024);
      gload_lds16(bj1 + off, (char*)&Bsl[buf][h][0] + 8192 + w * 1024);
    }
  };

  bf16x8 Ar[4][2], Bq[2][2][2];

  auto readA = [&](int buf, int r) {
    const char* base = (const char*)&Asl[buf][wm][0] + lofs;
#pragma unroll
    for (int i = 0; i < 4; ++i)
#pragma unroll
      for (int kk = 0; kk < 2; ++kk)
        Ar[i][kk] = *(const bf16x8*)(base + ((r * 4 + i) * 2 + kk) * 1024);
  };
  auto readB = [&](int buf, int c) {
    const char* base = (const char*)&Bsl[buf][c][0] + lofs;
#pragma unroll
    for (int j = 0; j < 2; ++j)
#pragma unroll
      for (int kk = 0; kk < 2; ++kk)
        Bq[c][j][kk] = *(const bf16x8*)(base + ((2 * wn + j) * 2 + kk) * 1024);
  };
  auto mfmaQ = [&](int r, int c) {
    __builtin_amdgcn_s_setprio(1);
#pragma unroll
    for (int i = 0; i < 4; ++i)
#pragma unroll
      for (int j = 0; j < 2; ++j) {
        int m = r * 4 + i, n = c * 2 + j;
        acc[m][n] = __builtin_amdgcn_mfma_f32_16x16x32_bf16(Ar[i][0], Bq[c][j][0], acc[m][n], 0, 0, 0);
        acc[m][n] = __builtin_amdgcn_mfma_f32_16x16x32_bf16(Ar[i][1], Bq[c][j][1], acc[m][n], 0, 0, 0);
      }
    __builtin_amdgcn_s_setprio(0);
  };

#define PH_SYNC() do { SBAR(); __builtin_amdgcn_s_barrier(); \
    asm volatile("s_waitcnt lgkmcnt(0)" ::: "memory"); SBAR(); } while (0)
#define PH_END() do { SBAR(); __builtin_amdgcn_s_barrier(); SBAR(); } while (0)

  stageH(0, 0, 0); stageH(0, 0, 1); stageH(1, 0, 0); stageH(1, 0, 1);
  stageH(1, 1, 0); stageH(0, 1, 0);
  asm volatile("s_waitcnt vmcnt(4)" ::: "memory");
  SBAR(); __builtin_amdgcn_s_barrier(); SBAR();

  for (int base = 0; base < T; base += 2) {
    readA(0, 0); readB(0, 0);
    stageH(0, base + 1, 1);
    PH_SYNC(); mfmaQ(0, 0); PH_END();
    readB(0, 1);
    stageH(1, base + 1, 1);
    PH_SYNC(); mfmaQ(0, 1); PH_END();
    readA(0, 1);
    stageH(1, base + 2, 0);
    PH_SYNC(); mfmaQ(1, 1); PH_END();
    stageH(0, base + 2, 0);
    PH_SYNC(); mfmaQ(1, 0);
    asm volatile("s_waitcnt vmcnt(4)" ::: "memory");
    PH_END();
    readA(1, 0); readB(1, 0);
    stageH(0, base + 2, 1);
    PH_SYNC(); mfmaQ(0, 0); PH_END();
    readB(1, 1);
    stageH(1, base + 2, 1);
    PH_SYNC(); mfmaQ(0, 1); PH_END();
    readA(1, 1);
    stageH(1, base + 3, 0);
    PH_SYNC(); mfmaQ(1, 1); PH_END();
    stageH(0, base + 3, 0);
    PH_SYNC(); mfmaQ(1, 0);
    asm volatile("s_waitcnt vmcnt(4)" ::: "memory");
    PH_END();
  }

#undef PH_SYNC
#undef PH_END

  bool doRope = (EPI == 0) && (n0 < 6144);
#pragma unroll
  for (int m = 0; m < 8; ++m)
#pragma unroll
    for (int jj = 0; jj < 4; ++jj) {
      int row = m0 + wm * 128 + m * 16 + l4 * 4 + jj;
      int s2 = row & 2047;
#pragma unroll
      for (int j = 0; j < 2; ++j) {
        float lo = acc[m][j][jj];
        float hi = acc[m][2 + j][jj];
        int cl = wn * 32 + j * 16 + l15;
        if (EPI == 0) {
          if (doRope) {
            int d = cl;
            float co = cosT[s2 * 128 + d];
            float si = sinT[s2 * 128 + d];
            float o0 = lo * co - hi * si;
            float o1 = hi * co + lo * si;
            lo = o0; hi = o1;
          }
          U16* cp = (U16*)Cv + (long)row * N + n0 + cl;
          cp[0] = f2bf(lo);
          cp[128] = f2bf(hi);
        } else {
          float* cp = (float*)Cv + (long)row * N + n0 + cl;
          cp[0] = lo;
          cp[128] = hi;
        }
      }
    }
}

// ---------------- banded GQA attention (v7: lane-ordered granules) ----------
__global__ __launch_bounds__(256) void k_attn(const U16* __restrict__ QKV,
                                              const U16* __restrict__ VT,
                                              U16* __restrict__ O) {
  __shared__ __align__(16) U16 Ks[2][32 * 256];
  __shared__ __align__(16) U16 Vs[2][256 * 32];
  __shared__ __align__(16) U16 Plds[4][16 * 40];
  int t = threadIdx.x, lane = t & 63, w = t >> 6;
  int flat = blockIdx.x + 32 * (blockIdx.y + 16 * blockIdx.z);
  int l = (flat & 7) * 128 + (flat >> 3);
  int qb = l & 31, h = (l >> 5) & 15, b = l >> 9;
  int s0 = qb * 64;
  int kvh = h >> 1;
  long rowOff = (long)b * 2048 * 8192;
  const U16* Qb = QKV + rowOff + h * 256;
  const U16* Kb = QKV + rowOff + 4096 + kvh * 256;
  const U16* VTb = VT + (long)(b * 8 + kvh) * 64 * 8192;

  int l15 = lane & 15, l4 = lane >> 4;
  int lofs = lane * 16;                      // lane-ordered granule read

  bf16x8 qf[8];
  {
    const U16* qp = Qb + (long)(s0 + w * 16 + l15) * 8192 + l4 * 8;
#pragma unroll
    for (int kc = 0; kc < 8; ++kc) qf[kc] = *(const bf16x8*)(qp + kc * 32);
  }
  asm volatile("s_waitcnt vmcnt(0)" ::: "memory");

  f32x4 acc[16] = {};
  float mrun = -1e30f, lrun = 0.0f;
  int qpos = s0 + w * 16 + l15;
  int qlo = s0 + w * 16, qhi = qlo + 15;

  int kstart = s0 - 1024; if (kstart < 0) kstart = 0;
  int kend = s0 + 64 + 1024; if (kend > 2048) kend = 2048;

  // staging source: granule g=lane holds data for read-lane g
  int sl15 = t & 15, sl4 = (t >> 4) & 3;
  int offK[4], offV[4];
#pragma unroll
  for (int i = 0; i < 4; ++i) {
    int f = i * 4 + w;
    offK[i] = ((f >> 3) * 16 + sl15) * 8192 + (f & 7) * 32 + sl4 * 8;
    offV[i] = (f * 16 + sl15) * 32 + sl4 * 8;
  }

  const U16* kb = Kb + (long)kstart * 8192;
  const U16* vt0 = VTb + (long)(kstart >> 5) * 8192;

  auto stage = [&](int buf) {
#pragma unroll
    for (int i = 0; i < 4; ++i)
      gload_lds16(kb + offK[i], (char*)&Ks[buf][0] + i * 4096 + w * 1024);
#pragma unroll
    for (int i = 0; i < 4; ++i)
      gload_lds16(vt0 + offV[i], (char*)&Vs[buf][0] + i * 4096 + w * 1024);
    kb += (long)32 * 8192;
    vt0 += 8192;
  };

  auto compute = [&](int buf, int k0) {
    f32x4 sAcc[2] = {};
    const char* Kc = (const char*)&Ks[buf][0] + lofs;
    __builtin_amdgcn_s_setprio(1);
#pragma unroll
    for (int kc = 0; kc < 8; ++kc) {
      bf16x8 a0 = *(const bf16x8*)(Kc + kc * 1024);
      bf16x8 a1 = *(const bf16x8*)(Kc + (8 + kc) * 1024);
      sAcc[0] = __builtin_amdgcn_mfma_f32_16x16x32_bf16(a0, qf[kc], sAcc[0], 0, 0, 0);
      sAcc[1] = __builtin_amdgcn_mfma_f32_16x16x32_bf16(a1, qf[kc], sAcc[1], 0, 0, 0);
    }
    __builtin_amdgcn_s_setprio(0);
    float sv[8];
#pragma unroll
    for (int mp = 0; mp < 2; ++mp)
#pragma unroll
      for (int jj = 0; jj < 4; ++jj) {
        float ex = __expf(sAcc[mp][jj] * 0.0025f);
        sv[mp * 4 + jj] = fmaf(-100.0f, __builtin_amdgcn_rcpf(ex + 1.0f), 50.0f);
      }
    bool full = ((qhi - k0) <= 1024) && ((k0 + 31 - qlo) <= 1024);
    if (!full) {
#pragma unroll
      for (int mp = 0; mp < 2; ++mp)
#pragma unroll
        for (int jj = 0; jj < 4; ++jj) {
          int key = k0 + mp * 16 + l4 * 4 + jj;
          int dd = qpos - key;
          if (dd < -1024 || dd > 1024) sv[mp * 4 + jj] = -3e38f;
        }
    }
    float tmax = sv[0];
#pragma unroll
    for (int i = 1; i < 8; ++i) tmax = fmaxf(tmax, sv[i]);
    tmax = fmaxf(tmax, __shfl_xor(tmax, 16));
    tmax = fmaxf(tmax, __shfl_xor(tmax, 32));
    bool skipall = __all((tmax <= mrun + 8.0f) ? 1 : 0) != 0;
    float mnew = skipall ? mrun : fmaxf(mrun, tmax);
    float pex[8];
    float psum = 0.0f;
#pragma unroll
    for (int i = 0; i < 8; ++i) { pex[i] = __expf(sv[i] - mnew); psum += pex[i]; }
    psum += __shfl_xor(psum, 16);
    psum += __shfl_xor(psum, 32);
    if (skipall) {
      lrun += psum;
    } else {
      float esc = __expf(mrun - mnew);
      f32x4 ev;
#pragma unroll
      for (int jj = 0; jj < 4; ++jj) ev[jj] = __shfl(esc, l4 * 4 + jj);
#pragma unroll
      for (int n = 0; n < 16; ++n) acc[n] *= ev;
      lrun = lrun * esc + psum;
      mrun = mnew;
    }
#pragma unroll
    for (int mp = 0; mp < 2; ++mp)
#pragma unroll
      for (int j2 = 0; j2 < 2; ++j2) {
        unsigned lo = f2bf(pex[mp * 4 + j2 * 2]);
        unsigned hi = f2bf(pex[mp * 4 + j2 * 2 + 1]);
        *(unsigned*)&Plds[w][l15 * 40 + mp * 16 + l4 * 4 + j2 * 2] = lo | (hi << 16);
      }
    asm volatile("s_waitcnt lgkmcnt(0)" ::: "memory");
    __builtin_amdgcn_sched_barrier(0);
    bf16x8 pa = *(const bf16x8*)&Plds[w][l15 * 40 + l4 * 8];
    const char* Vc = (const char*)&Vs[buf][0] + lofs;
    __builtin_amdgcn_s_setprio(1);
#pragma unroll
    for (int n = 0; n < 16; ++n) {
      bf16x8 vb = *(const bf16x8*)(Vc + n * 1024);
      acc[n] = __builtin_amdgcn_mfma_f32_16x16x32_bf16(pa, vb, acc[n], 0, 0, 0);
    }
    __builtin_amdgcn_s_setprio(0);
  };

  int cur = 0;
  stage(0);
  for (int k0 = kstart; k0 < kend - 32; k0 += 32) {
    stage(cur ^ 1);
    asm volatile("s_waitcnt vmcnt(8)" ::: "memory");
    __builtin_amdgcn_s_barrier();
    __builtin_amdgcn_sched_barrier(0);
    compute(cur, k0);
    __builtin_amdgcn_s_barrier();
    cur ^= 1;
  }
  asm volatile("s_waitcnt vmcnt(0)" ::: "memory");
  __builtin_amdgcn_s_barrier();
  __builtin_amdgcn_sched_barrier(0);
  compute(cur, kend - 32);

  f32x4 linv;
#pragma unroll
  for (int jj = 0; jj < 4; ++jj) linv[jj] = 1.0f / __shfl(lrun, l4 * 4 + jj);
#pragma unroll
  for (int jj = 0; jj < 4; ++jj) {
    int row = s0 + w * 16 + l4 * 4 + jj;
    U16* op = O + ((long)b * 2048 + row) * 4096 + h * 256 + l15;
#pragma unroll
    for (int n = 0; n < 16; ++n) op[n * 16] = f2bf(acc[n][jj] * linv[jj]);
  }
}

// ----------------------------------------------------------------------------
extern "C" void kernel_launch(void* const* d_in, const int* in_sizes, int n_in,
                              void* d_out, int out_size, void* d_ws, size_t ws_size,
                              hipStream_t stream) {
  if (n_in < 5) return;
  const float* hid = (const float*)d_in[0];
  const float* Wq  = (const float*)d_in[1];
  const float* Wk  = (const float*)d_in[2];
  const float* Wv  = (const float*)d_in[3];
  const float* Wo  = (const float*)d_in[4];

  char* ws = (char*)d_ws;
  size_t off = 0;
  auto alloc = [&](size_t bytes) {
    char* p = ws + off;
    off += (bytes + 255) & ~(size_t)255;
    return p;
  };
  float* cosT = (float*)alloc((size_t)2048 * 128 * 4);
  float* sinT = (float*)alloc((size_t)2048 * 128 * 4);
  U16*   Xb   = (U16*)alloc((size_t)4096 * 3584 * 2);   // reused: VT, then Wot
  U16*   Wt   = (U16*)alloc((size_t)8192 * 3584 * 2);   // reused: AttO
  U16*   QKV  = (U16*)alloc((size_t)4096 * 8192 * 2);
  if (off > ws_size) return;
  U16* VT   = Xb;
  U16* Wot  = Xb;
  U16* AttO = Wt;

  k_convert<<<7168, 256, 0, stream>>>(hid, Xb, (long)4096 * 3584);
  k_transpose<<<dim3(128, 112), 256, 0, stream>>>(Wq, Wt, 3584, 4096);
  k_transpose<<<dim3(64, 112), 256, 0, stream>>>(Wk, Wt + (size_t)4096 * 3584, 3584, 2048);
  k_transpose<<<dim3(64, 112), 256, 0, stream>>>(Wv, Wt + (size_t)6144 * 3584, 3584, 2048);
  k_rope_tables<<<1024, 256, 0, stream>>>(cosT, sinT);
  k_gemm8<0><<<dim3(32, 16), 512, 0, stream>>>(Xb, Wt, QKV, cosT, sinT, 4096, 8192, 3584);
  k_vtrans<<<dim3(64, 8, 16), 256, 0, stream>>>(QKV, VT);
  k_attn<<<dim3(32, 16, 2), 256, 0, stream>>>(QKV, VT, AttO);
  k_transpose<<<dim3(112, 128), 256, 0, stream>>>(Wo, Wot, 4096, 3584);
  k_gemm8<1><<<dim3(14, 16), 512, 0, stream>>>(AttO, Wot, d_out, cosT, sinT, 4096, 3584, 4096);
}

// Round 15
// 686.317 us; speedup vs baseline: 1.0863x; 1.0863x over previous
//
#include <hip/hip_runtime.h>
#include <stdint.h>

typedef unsigned short U16;
typedef float f32x4 __attribute__((ext_vector_type(4)));
typedef __bf16 bf16x8 __attribute__((ext_vector_type(8)));

static __device__ __forceinline__ U16 f2bf(float x) {
  union { float f; unsigned u; } v; v.f = x;
  unsigned r = v.u + 0x7FFFu + ((v.u >> 16) & 1u);
  return (U16)(r >> 16);
}
static __device__ __forceinline__ float bf2f(U16 h) {
  union { unsigned u; float f; } v; v.u = ((unsigned)h) << 16;
  return v.f;
}

static __device__ __forceinline__ void gload_lds16(const void* g, void* l) {
  __builtin_amdgcn_global_load_lds(
      (const __attribute__((address_space(1))) void*)g,
      (__attribute__((address_space(3))) void*)l, 16, 0, 0);
}

#define SBAR() __builtin_amdgcn_sched_barrier(0)

// ---------------- hidden (fp32) -> bf16 -------------------------------------
__global__ __launch_bounds__(256) void k_convert(const float* __restrict__ src,
                                                 U16* __restrict__ dst, long n) {
  long base = ((long)blockIdx.x * 256 + threadIdx.x) * 8;
  if (base >= n) return;
  const float4* s = (const float4*)(src + base);
  float4 a = s[0], b = s[1];
  U16 o[8] = { f2bf(a.x), f2bf(a.y), f2bf(a.z), f2bf(a.w),
               f2bf(b.x), f2bf(b.y), f2bf(b.z), f2bf(b.w) };
  *(uint4*)(dst + base) = *(const uint4*)o;
}

// ---------------- W[K][N] (fp32) -> Wt[N][K] bf16 ----------------------------
__global__ __launch_bounds__(256) void k_transpose(const float* __restrict__ src,
                                                   U16* __restrict__ dst,
                                                   int K, int N) {
  __shared__ U16 tile[32][33];
  int n0 = blockIdx.x * 32, k0 = blockIdx.y * 32;
  int tx = threadIdx.x & 31, ty = threadIdx.x >> 5;
#pragma unroll
  for (int r = 0; r < 4; ++r) {
    int k = k0 + ty + r * 8;
    tile[ty + r * 8][tx] = f2bf(src[(long)k * N + n0 + tx]);
  }
  __syncthreads();
#pragma unroll
  for (int r = 0; r < 4; ++r) {
    int n = n0 + ty + r * 8;
    dst[(long)n * K + k0 + tx] = tile[tx][ty + r * 8];
  }
}

// ---- V section of QKV -> VT tiled [bk][sTile=64][d=256][s32=32] bf16 -------
__global__ __launch_bounds__(256) void k_vtrans(const U16* __restrict__ QKV,
                                                U16* __restrict__ VT) {
  __shared__ U16 tile[32][33];
  int s0 = blockIdx.x * 32, d0 = blockIdx.y * 32, bk = blockIdx.z;
  int b = bk >> 3, kvh = bk & 7;
  int tx = threadIdx.x & 31, ty = threadIdx.x >> 5;
  const U16* src = QKV + (long)(b * 2048) * 8192 + 6144 + kvh * 256;
#pragma unroll
  for (int r = 0; r < 4; ++r) {
    int s = s0 + ty + r * 8;
    tile[ty + r * 8][tx] = src[(long)s * 8192 + d0 + tx];
  }
  __syncthreads();
  long tbase = ((long)bk * 64 + (s0 >> 5)) * 8192;
#pragma unroll
  for (int r = 0; r < 4; ++r) {
    int d = d0 + ty + r * 8;
    VT[tbase + d * 32 + tx] = tile[tx][ty + r * 8];
  }
}

// ---------------- RoPE tables (fp32) ----------------------------------------
__global__ __launch_bounds__(256) void k_rope_tables(float* __restrict__ cosT,
                                                     float* __restrict__ sinT) {
  int i = blockIdx.x * 256 + threadIdx.x;
  int s = i >> 7, d = i & 127;
  float freq = expf(-9.210340371976184f * (float)d / 128.0f);
  float ang = (float)s * freq;
  cosT[i] = cosf(ang);
  sinT[i] = sinf(ang);
}

// ---------------- GEMM v6 (r13 revert): 256x256, BK=64, 8-PHASE + rope ------
// Fragment-linear LDS, coalesced staging (4 consecutive lanes per 64B row
// segment). In-group read aliasing (2.2e7 counter) is measured-benign (r14).
template <int EPI>
__global__ __launch_bounds__(512, 1) void k_gemm8(const U16* __restrict__ A,
                                                  const U16* __restrict__ Bt,
                                                  void* __restrict__ Cv,
                                                  const float* __restrict__ cosT,
                                                  const float* __restrict__ sinT,
                                                  int M, int N, int K) {
  __shared__ __align__(16) U16 Asl[2][2][128 * 64];
  __shared__ __align__(16) U16 Bsl[2][2][128 * 64];
  int nwg = gridDim.x * gridDim.y;
  int flat = blockIdx.y * gridDim.x + blockIdx.x;
  int cpx = nwg >> 3;
  int swz = (flat & 7) * cpx + (flat >> 3);
  int bx = swz % gridDim.x, by = swz / gridDim.x;
  int t = threadIdx.x, lane = t & 63, w = t >> 6;
  int m0 = by * 256, n0 = bx * 256;
  int wm = w >> 2, wn = w & 3;
  int l15 = lane & 15, l4 = lane >> 4;
  int lofs = (l15 * 4 + l4) * 16;

  f32x4 acc[8][4] = {};
  int T = K >> 6;

  int sr = lane >> 2, sc4 = (lane & 3) * 8;
  int fA0 = (w >> 1) * 16 + sr, kA0 = (w & 1) * 32 + sc4;
  int fA1 = ((8 + w) >> 1) * 16 + sr, kA1 = ((8 + w) & 1) * 32 + sc4;
  const U16* aj0 = A + (long)(m0 + fA0) * K + kA0;
  const U16* aj1 = A + (long)(m0 + fA1) * K + kA1;
  const U16* bj0 = Bt + (long)(n0 + fA0) * K + kA0;
  const U16* bj1 = Bt + (long)(n0 + fA1) * K + kA1;

  auto stageH = [&](int op, int kt, int h) {
    int buf = kt & 1;
    int ktc = (kt < T) ? kt : 0;
    long off = (long)ktc * 64 + (long)h * 128 * K;
    if (op == 0) {
      gload_lds16(aj0 + off, (char*)&Asl[buf][h][0] + w * 1024);
      gload_lds16(aj1 + off, (char*)&Asl[buf][h][0] + 8192 + w * 1024);
    } else {
      gload_lds16(bj0 + off, (char*)&Bsl[buf][h][0] + w * 1024);
      gload_lds16(bj1 + off, (char*)&Bsl[buf][h][0] + 8192 + w * 1024);
    }
  };

  bf16x8 Ar[4][2], Bq[2][2][2];

  auto readA = [&](int buf, int r) {
    const char* base = (const char*)&Asl[buf][wm][0] + lofs;
#pragma unroll
    for (int i = 0; i < 4; ++i)
#pragma unroll
      for (int kk = 0; kk < 2; ++kk)
        Ar[i][kk] = *(const bf16x8*)(base + ((r * 4 + i) * 2 + kk) * 1024);
  };
  auto readB = [&](int buf, int c) {
    const char* base = (const char*)&Bsl[buf][c][0] + lofs;
#pragma unroll
    for (int j = 0; j < 2; ++j)
#pragma unroll
      for (int kk = 0; kk < 2; ++kk)
        Bq[c][j][kk] = *(const bf16x8*)(base + ((2 * wn + j) * 2 + kk) * 1024);
  };
  auto mfmaQ = [&](int r, int c) {
    __builtin_amdgcn_s_setprio(1);
#pragma unroll
    for (int i = 0; i < 4; ++i)
#pragma unroll
      for (int j = 0; j < 2; ++j) {
        int m = r * 4 + i, n = c * 2 + j;
        acc[m][n] = __builtin_amdgcn_mfma_f32_16x16x32_bf16(Ar[i][0], Bq[c][j][0], acc[m][n], 0, 0, 0);
        acc[m][n] = __builtin_amdgcn_mfma_f32_16x16x32_bf16(Ar[i][1], Bq[c][j][1], acc[m][n], 0, 0, 0);
      }
    __builtin_amdgcn_s_setprio(0);
  };

#define PH_SYNC() do { SBAR(); __builtin_amdgcn_s_barrier(); \
    asm volatile("s_waitcnt lgkmcnt(0)" ::: "memory"); SBAR(); } while (0)
#define PH_END() do { SBAR(); __builtin_amdgcn_s_barrier(); SBAR(); } while (0)

  stageH(0, 0, 0); stageH(0, 0, 1); stageH(1, 0, 0); stageH(1, 0, 1);
  stageH(1, 1, 0); stageH(0, 1, 0);
  asm volatile("s_waitcnt vmcnt(4)" ::: "memory");
  SBAR(); __builtin_amdgcn_s_barrier(); SBAR();

  for (int base = 0; base < T; base += 2) {
    readA(0, 0); readB(0, 0);
    stageH(0, base + 1, 1);
    PH_SYNC(); mfmaQ(0, 0); PH_END();
    readB(0, 1);
    stageH(1, base + 1, 1);
    PH_SYNC(); mfmaQ(0, 1); PH_END();
    readA(0, 1);
    stageH(1, base + 2, 0);
    PH_SYNC(); mfmaQ(1, 1); PH_END();
    stageH(0, base + 2, 0);
    PH_SYNC(); mfmaQ(1, 0);
    asm volatile("s_waitcnt vmcnt(4)" ::: "memory");
    PH_END();
    readA(1, 0); readB(1, 0);
    stageH(0, base + 2, 1);
    PH_SYNC(); mfmaQ(0, 0); PH_END();
    readB(1, 1);
    stageH(1, base + 2, 1);
    PH_SYNC(); mfmaQ(0, 1); PH_END();
    readA(1, 1);
    stageH(1, base + 3, 0);
    PH_SYNC(); mfmaQ(1, 1); PH_END();
    stageH(0, base + 3, 0);
    PH_SYNC(); mfmaQ(1, 0);
    asm volatile("s_waitcnt vmcnt(4)" ::: "memory");
    PH_END();
  }

#undef PH_SYNC
#undef PH_END

  bool doRope = (EPI == 0) && (n0 < 6144);
#pragma unroll
  for (int m = 0; m < 8; ++m)
#pragma unroll
    for (int jj = 0; jj < 4; ++jj) {
      int row = m0 + wm * 128 + m * 16 + l4 * 4 + jj;
      int s2 = row & 2047;
#pragma unroll
      for (int j = 0; j < 2; ++j) {
        float lo = acc[m][j][jj];
        float hi = acc[m][2 + j][jj];
        int cl = wn * 32 + j * 16 + l15;
        if (EPI == 0) {
          if (doRope) {
            int d = cl;
            float co = cosT[s2 * 128 + d];
            float si = sinT[s2 * 128 + d];
            float o0 = lo * co - hi * si;
            float o1 = hi * co + lo * si;
            lo = o0; hi = o1;
          }
          U16* cp = (U16*)Cv + (long)row * N + n0 + cl;
          cp[0] = f2bf(lo);
          cp[128] = f2bf(hi);
        } else {
          float* cp = (float*)Cv + (long)row * N + n0 + cl;
          cp[0] = lo;
          cp[128] = hi;
        }
      }
    }
}

// ---------------- banded GQA attention (v8: 128 q-rows, 8 waves) ------------
// 512 threads; wave w owns q rows s0+w*16..+15, s0 = qb*128. Same per-wave
// math as v6; K/V staging amortized 2x; 4 waves/SIMD hide serial softmax.
// Fully-masked tiles are exact no-ops on (m,l,acc) -> per-row bitwise
// identical to v6. LDS 74.2KB -> 2 blocks/CU.
__global__ __launch_bounds__(512, 4) void k_attn(const U16* __restrict__ QKV,
                                                 const U16* __restrict__ VT,
                                                 U16* __restrict__ O) {
  __shared__ __align__(16) U16 Ks[2][32 * 256];
  __shared__ __align__(16) U16 Vs[2][256 * 32];
  __shared__ __align__(16) U16 Plds[8][16 * 40];
  int t = threadIdx.x, lane = t & 63, w = t >> 6;
  int flat = blockIdx.x + 16 * (blockIdx.y + 16 * blockIdx.z);
  int l = (flat & 7) * 64 + (flat >> 3);
  int qb = l & 15, h = (l >> 4) & 15, b = l >> 8;
  int s0 = qb * 128;
  int kvh = h >> 1;
  long rowOff = (long)b * 2048 * 8192;
  const U16* Qb = QKV + rowOff + h * 256;
  const U16* Kb = QKV + rowOff + 4096 + kvh * 256;
  const U16* VTb = VT + (long)(b * 8 + kvh) * 64 * 8192;

  int l15 = lane & 15, l4 = lane >> 4;
  int lofs = (l15 * 4 + l4) * 16;

  bf16x8 qf[8];
  {
    const U16* qp = Qb + (long)(s0 + w * 16 + l15) * 8192 + l4 * 8;
#pragma unroll
    for (int kc = 0; kc < 8; ++kc) qf[kc] = *(const bf16x8*)(qp + kc * 32);
  }
  asm volatile("s_waitcnt vmcnt(0)" ::: "memory");

  f32x4 acc[16] = {};
  float mrun = -1e30f, lrun = 0.0f;
  int qpos = s0 + w * 16 + l15;
  int qlo = s0 + w * 16, qhi = qlo + 15;

  int kstart = s0 - 1024; if (kstart < 0) kstart = 0;
  int kend = s0 + 128 + 1024; if (kend > 2048) kend = 2048;

  // staging (coalesced, r13-style): 4 consecutive lanes cover one 64B segment
  int sl15 = (lane >> 2) & 15, sl4 = lane & 3;
  int offK[2], offV[2];
#pragma unroll
  for (int i = 0; i < 2; ++i) {
    offK[i] = (i * 16 + sl15) * 8192 + w * 32 + sl4 * 8;
    offV[i] = ((i * 8 + w) * 16 + sl15) * 32 + sl4 * 8;
  }

  const U16* kb = Kb + (long)kstart * 8192;
  const U16* vt0 = VTb + (long)(kstart >> 5) * 8192;

  auto stage = [&](int buf) {
#pragma unroll
    for (int i = 0; i < 2; ++i)
      gload_lds16(kb + offK[i], (char*)&Ks[buf][0] + i * 8192 + w * 1024);
#pragma unroll
    for (int i = 0; i < 2; ++i)
      gload_lds16(vt0 + offV[i], (char*)&Vs[buf][0] + i * 8192 + w * 1024);
    kb += (long)32 * 8192;
    vt0 += 8192;
  };

  auto compute = [&](int buf, int k0) {
    f32x4 sAcc[2] = {};
    const char* Kc = (const char*)&Ks[buf][0] + lofs;
    __builtin_amdgcn_s_setprio(1);
#pragma unroll
    for (int kc = 0; kc < 8; ++kc) {
      bf16x8 a0 = *(const bf16x8*)(Kc + kc * 1024);
      bf16x8 a1 = *(const bf16x8*)(Kc + (8 + kc) * 1024);
      sAcc[0] = __builtin_amdgcn_mfma_f32_16x16x32_bf16(a0, qf[kc], sAcc[0], 0, 0, 0);
      sAcc[1] = __builtin_amdgcn_mfma_f32_16x16x32_bf16(a1, qf[kc], sAcc[1], 0, 0, 0);
    }
    __builtin_amdgcn_s_setprio(0);
    float sv[8];
#pragma unroll
    for (int mp = 0; mp < 2; ++mp)
#pragma unroll
      for (int jj = 0; jj < 4; ++jj) {
        float ex = __expf(sAcc[mp][jj] * 0.0025f);
        sv[mp * 4 + jj] = fmaf(-100.0f, __builtin_amdgcn_rcpf(ex + 1.0f), 50.0f);
      }
    bool full = ((qhi - k0) <= 1024) && ((k0 + 31 - qlo) <= 1024);
    if (!full) {
#pragma unroll
      for (int mp = 0; mp < 2; ++mp)
#pragma unroll
        for (int jj = 0; jj < 4; ++jj) {
          int key = k0 + mp * 16 + l4 * 4 + jj;
          int dd = qpos - key;
          if (dd < -1024 || dd > 1024) sv[mp * 4 + jj] = -3e38f;
        }
    }
    float tmax = sv[0];
#pragma unroll
    for (int i = 1; i < 8; ++i) tmax = fmaxf(tmax, sv[i]);
    tmax = fmaxf(tmax, __shfl_xor(tmax, 16));
    tmax = fmaxf(tmax, __shfl_xor(tmax, 32));
    bool skipall = __all((tmax <= mrun + 8.0f) ? 1 : 0) != 0;
    float mnew = skipall ? mrun : fmaxf(mrun, tmax);
    float pex[8];
    float psum = 0.0f;
#pragma unroll
    for (int i = 0; i < 8; ++i) { pex[i] = __expf(sv[i] - mnew); psum += pex[i]; }
    psum += __shfl_xor(psum, 16);
    psum += __shfl_xor(psum, 32);
    if (skipall) {
      lrun += psum;
    } else {
      float esc = __expf(mrun - mnew);
      f32x4 ev;
#pragma unroll
      for (int jj = 0; jj < 4; ++jj) ev[jj] = __shfl(esc, l4 * 4 + jj);
#pragma unroll
      for (int n = 0; n < 16; ++n) acc[n] *= ev;
      lrun = lrun * esc + psum;
      mrun = mnew;
    }
#pragma unroll
    for (int mp = 0; mp < 2; ++mp)
#pragma unroll
      for (int j2 = 0; j2 < 2; ++j2) {
        unsigned lo = f2bf(pex[mp * 4 + j2 * 2]);
        unsigned hi = f2bf(pex[mp * 4 + j2 * 2 + 1]);
        *(unsigned*)&Plds[w][l15 * 40 + mp * 16 + l4 * 4 + j2 * 2] = lo | (hi << 16);
      }
    asm volatile("s_waitcnt lgkmcnt(0)" ::: "memory");
    __builtin_amdgcn_sched_barrier(0);
    bf16x8 pa = *(const bf16x8*)&Plds[w][l15 * 40 + l4 * 8];
    const char* Vc = (const char*)&Vs[buf][0] + lofs;
    __builtin_amdgcn_s_setprio(1);
#pragma unroll
    for (int n = 0; n < 16; ++n) {
      bf16x8 vb = *(const bf16x8*)(Vc + n * 1024);
      acc[n] = __builtin_amdgcn_mfma_f32_16x16x32_bf16(pa, vb, acc[n], 0, 0, 0);
    }
    __builtin_amdgcn_s_setprio(0);
  };

  int cur = 0;
  stage(0);
  for (int k0 = kstart; k0 < kend - 32; k0 += 32) {
    stage(cur ^ 1);
    asm volatile("s_waitcnt vmcnt(4)" ::: "memory");
    __builtin_amdgcn_s_barrier();
    __builtin_amdgcn_sched_barrier(0);
    compute(cur, k0);
    __builtin_amdgcn_s_barrier();
    cur ^= 1;
  }
  asm volatile("s_waitcnt vmcnt(0)" ::: "memory");
  __builtin_amdgcn_s_barrier();
  __builtin_amdgcn_sched_barrier(0);
  compute(cur, kend - 32);

  f32x4 linv;
#pragma unroll
  for (int jj = 0; jj < 4; ++jj) linv[jj] = 1.0f / __shfl(lrun, l4 * 4 + jj);
#pragma unroll
  for (int jj = 0; jj < 4; ++jj) {
    int row = s0 + w * 16 + l4 * 4 + jj;
    U16* op = O + ((long)b * 2048 + row) * 4096 + h * 256 + l15;
#pragma unroll
    for (int n = 0; n < 16; ++n) op[n * 16] = f2bf(acc[n][jj] * linv[jj]);
  }
}

// ----------------------------------------------------------------------------
extern "C" void kernel_launch(void* const* d_in, const int* in_sizes, int n_in,
                              void* d_out, int out_size, void* d_ws, size_t ws_size,
                              hipStream_t stream) {
  if (n_in < 5) return;
  const float* hid = (const float*)d_in[0];
  const float* Wq  = (const float*)d_in[1];
  const float* Wk  = (const float*)d_in[2];
  const float* Wv  = (const float*)d_in[3];
  const float* Wo  = (const float*)d_in[4];

  char* ws = (char*)d_ws;
  size_t off = 0;
  auto alloc = [&](size_t bytes) {
    char* p = ws + off;
    off += (bytes + 255) & ~(size_t)255;
    return p;
  };
  float* cosT = (float*)alloc((size_t)2048 * 128 * 4);
  float* sinT = (float*)alloc((size_t)2048 * 128 * 4);
  U16*   Xb   = (U16*)alloc((size_t)4096 * 3584 * 2);   // reused: VT, then Wot
  U16*   Wt   = (U16*)alloc((size_t)8192 * 3584 * 2);   // reused: AttO
  U16*   QKV  = (U16*)alloc((size_t)4096 * 8192 * 2);
  if (off > ws_size) return;
  U16* VT   = Xb;
  U16* Wot  = Xb;
  U16* AttO = Wt;

  k_convert<<<7168, 256, 0, stream>>>(hid, Xb, (long)4096 * 3584);
  k_transpose<<<dim3(128, 112), 256, 0, stream>>>(Wq, Wt, 3584, 4096);
  k_transpose<<<dim3(64, 112), 256, 0, stream>>>(Wk, Wt + (size_t)4096 * 3584, 3584, 2048);
  k_transpose<<<dim3(64, 112), 256, 0, stream>>>(Wv, Wt + (size_t)6144 * 3584, 3584, 2048);
  k_rope_tables<<<1024, 256, 0, stream>>>(cosT, sinT);
  k_gemm8<0><<<dim3(32, 16), 512, 0, stream>>>(Xb, Wt, QKV, cosT, sinT, 4096, 8192, 3584);
  k_vtrans<<<dim3(64, 8, 16), 256, 0, stream>>>(QKV, VT);
  k_attn<<<dim3(16, 16, 2), 512, 0, stream>>>(QKV, VT, AttO);
  k_transpose<<<dim3(112, 128), 256, 0, stream>>>(Wo, Wot, 4096, 3584);
  k_gemm8<1><<<dim3(14, 16), 512, 0, stream>>>(AttO, Wot, d_out, cosT, sinT, 4096, 3584, 4096);
}

// Round 16
// 629.158 us; speedup vs baseline: 1.1850x; 1.0908x over previous
//
#include <hip/hip_runtime.h>
#include <stdint.h>

typedef unsigned short U16;
typedef float f32x4 __attribute__((ext_vector_type(4)));
typedef __bf16 bf16x8 __attribute__((ext_vector_type(8)));

static __device__ __forceinline__ U16 f2bf(float x) {
  union { float f; unsigned u; } v; v.f = x;
  unsigned r = v.u + 0x7FFFu + ((v.u >> 16) & 1u);
  return (U16)(r >> 16);
}
static __device__ __forceinline__ float bf2f(U16 h) {
  union { unsigned u; float f; } v; v.u = ((unsigned)h) << 16;
  return v.f;
}

static __device__ __forceinline__ void gload_lds16(const void* g, void* l) {
  __builtin_amdgcn_global_load_lds(
      (const __attribute__((address_space(1))) void*)g,
      (__attribute__((address_space(3))) void*)l, 16, 0, 0);
}

#define SBAR() __builtin_amdgcn_sched_barrier(0)

// ---------------- hidden (fp32) -> bf16 -------------------------------------
__global__ __launch_bounds__(256) void k_convert(const float* __restrict__ src,
                                                 U16* __restrict__ dst, long n) {
  long base = ((long)blockIdx.x * 256 + threadIdx.x) * 8;
  if (base >= n) return;
  const float4* s = (const float4*)(src + base);
  float4 a = s[0], b = s[1];
  U16 o[8] = { f2bf(a.x), f2bf(a.y), f2bf(a.z), f2bf(a.w),
               f2bf(b.x), f2bf(b.y), f2bf(b.z), f2bf(b.w) };
  *(uint4*)(dst + base) = *(const uint4*)o;
}

// ---------------- W[K][N] (fp32) -> Wt[N][K] bf16 ----------------------------
__global__ __launch_bounds__(256) void k_transpose(const float* __restrict__ src,
                                                   U16* __restrict__ dst,
                                                   int K, int N) {
  __shared__ U16 tile[32][33];
  int n0 = blockIdx.x * 32, k0 = blockIdx.y * 32;
  int tx = threadIdx.x & 31, ty = threadIdx.x >> 5;
#pragma unroll
  for (int r = 0; r < 4; ++r) {
    int k = k0 + ty + r * 8;
    tile[ty + r * 8][tx] = f2bf(src[(long)k * N + n0 + tx]);
  }
  __syncthreads();
#pragma unroll
  for (int r = 0; r < 4; ++r) {
    int n = n0 + ty + r * 8;
    dst[(long)n * K + k0 + tx] = tile[tx][ty + r * 8];
  }
}

// ---- V section of QKV -> VT tiled [bk][sTile=64][d=256][s32=32] bf16 -------
__global__ __launch_bounds__(256) void k_vtrans(const U16* __restrict__ QKV,
                                                U16* __restrict__ VT) {
  __shared__ U16 tile[32][33];
  int s0 = blockIdx.x * 32, d0 = blockIdx.y * 32, bk = blockIdx.z;
  int b = bk >> 3, kvh = bk & 7;
  int tx = threadIdx.x & 31, ty = threadIdx.x >> 5;
  const U16* src = QKV + (long)(b * 2048) * 8192 + 6144 + kvh * 256;
#pragma unroll
  for (int r = 0; r < 4; ++r) {
    int s = s0 + ty + r * 8;
    tile[ty + r * 8][tx] = src[(long)s * 8192 + d0 + tx];
  }
  __syncthreads();
  long tbase = ((long)bk * 64 + (s0 >> 5)) * 8192;
#pragma unroll
  for (int r = 0; r < 4; ++r) {
    int d = d0 + ty + r * 8;
    VT[tbase + d * 32 + tx] = tile[tx][ty + r * 8];
  }
}

// ---------------- RoPE tables (fp32) ----------------------------------------
__global__ __launch_bounds__(256) void k_rope_tables(float* __restrict__ cosT,
                                                     float* __restrict__ sinT) {
  int i = blockIdx.x * 256 + threadIdx.x;
  int s = i >> 7, d = i & 127;
  float freq = expf(-9.210340371976184f * (float)d / 128.0f);
  float ang = (float)s * freq;
  cosT[i] = cosf(ang);
  sinT[i] = sinf(ang);
}

// ---------------- GEMM v8: 256x256, BK=64, 8-PHASE, chunk-XOR swizzle -------
// Granule (pr,pc) of each 1KB sub-block holds row pr, k-chunk pc^((pr>>1)&3).
// Staging: lane L covers row L>>2, chunk (L&3)^((L>>3)&3) -> 4 consecutive
// lanes still cover one 64B row segment (coalescing preserved). Read: lane l
// fetches granule (l&15)*4 + ((l>>4)^((l>>1)&3)) -> 2 lanes/bank-quad per
// 16-lane group (2-way = free). Fragment bits per lane unchanged -> output
// bitwise identical.
template <int EPI>
__global__ __launch_bounds__(512, 1) void k_gemm8(const U16* __restrict__ A,
                                                  const U16* __restrict__ Bt,
                                                  void* __restrict__ Cv,
                                                  const float* __restrict__ cosT,
                                                  const float* __restrict__ sinT,
                                                  int M, int N, int K) {
  __shared__ __align__(16) U16 Asl[2][2][128 * 64];
  __shared__ __align__(16) U16 Bsl[2][2][128 * 64];
  int nwg = gridDim.x * gridDim.y;
  int flat = blockIdx.y * gridDim.x + blockIdx.x;
  int cpx = nwg >> 3;
  int swz = (flat & 7) * cpx + (flat >> 3);
  int bx = swz % gridDim.x, by = swz / gridDim.x;
  int t = threadIdx.x, lane = t & 63, w = t >> 6;
  int m0 = by * 256, n0 = bx * 256;
  int wm = w >> 2, wn = w & 3;
  int l15 = lane & 15, l4 = lane >> 4;
  int lofs = ((lane & 15) * 4 + ((lane >> 4) ^ ((lane >> 1) & 3))) * 16;

  f32x4 acc[8][4] = {};
  int T = K >> 6;

  // staging: row L>>2, chunk (L&3)^((L>>3)&3) within the 64B row segment
  int sr = lane >> 2, sc4 = ((lane & 3) ^ ((lane >> 3) & 3)) * 8;
  int fA0 = (w >> 1) * 16 + sr, kA0 = (w & 1) * 32 + sc4;
  int fA1 = ((8 + w) >> 1) * 16 + sr, kA1 = ((8 + w) & 1) * 32 + sc4;
  const U16* aj0 = A + (long)(m0 + fA0) * K + kA0;
  const U16* aj1 = A + (long)(m0 + fA1) * K + kA1;
  const U16* bj0 = Bt + (long)(n0 + fA0) * K + kA0;
  const U16* bj1 = Bt + (long)(n0 + fA1) * K + kA1;

  auto stageH = [&](int op, int kt, int h) {
    int buf = kt & 1;
    int ktc = (kt < T) ? kt : 0;
    long off = (long)ktc * 64 + (long)h * 128 * K;
    if (op == 0) {
      gload_lds16(aj0 + off, (char*)&Asl[buf][h][0] + w * 1024);
      gload_lds16(aj1 + off, (char*)&Asl[buf][h][0] + 8192 + w * 1024);
    } else {
      gload_lds16(bj0 + off, (char*)&Bsl[buf][h][0] + w * 1024);
      gload_lds16(bj1 + off, (char*)&Bsl[buf][h][0] + 8192 + w * 1024);
    }
  };

  bf16x8 Ar[4][2], Bq[2][2][2];

  auto readA = [&](int buf, int r) {
    const char* base = (const char*)&Asl[buf][wm][0] + lofs;
#pragma unroll
    for (int i = 0; i < 4; ++i)
#pragma unroll
      for (int kk = 0; kk < 2; ++kk)
        Ar[i][kk] = *(const bf16x8*)(base + ((r * 4 + i) * 2 + kk) * 1024);
  };
  auto readB = [&](int buf, int c) {
    const char* base = (const char*)&Bsl[buf][c][0] + lofs;
#pragma unroll
    for (int j = 0; j < 2; ++j)
#pragma unroll
      for (int kk = 0; kk < 2; ++kk)
        Bq[c][j][kk] = *(const bf16x8*)(base + ((2 * wn + j) * 2 + kk) * 1024);
  };
  auto mfmaQ = [&](int r, int c) {
    __builtin_amdgcn_s_setprio(1);
#pragma unroll
    for (int i = 0; i < 4; ++i)
#pragma unroll
      for (int j = 0; j < 2; ++j) {
        int m = r * 4 + i, n = c * 2 + j;
        acc[m][n] = __builtin_amdgcn_mfma_f32_16x16x32_bf16(Ar[i][0], Bq[c][j][0], acc[m][n], 0, 0, 0);
        acc[m][n] = __builtin_amdgcn_mfma_f32_16x16x32_bf16(Ar[i][1], Bq[c][j][1], acc[m][n], 0, 0, 0);
      }
    __builtin_amdgcn_s_setprio(0);
  };

#define PH_SYNC() do { SBAR(); __builtin_amdgcn_s_barrier(); \
    asm volatile("s_waitcnt lgkmcnt(0)" ::: "memory"); SBAR(); } while (0)
#define PH_END() do { SBAR(); __builtin_amdgcn_s_barrier(); SBAR(); } while (0)

  stageH(0, 0, 0); stageH(0, 0, 1); stageH(1, 0, 0); stageH(1, 0, 1);
  stageH(1, 1, 0); stageH(0, 1, 0);
  asm volatile("s_waitcnt vmcnt(4)" ::: "memory");
  SBAR(); __builtin_amdgcn_s_barrier(); SBAR();

  for (int base = 0; base < T; base += 2) {
    readA(0, 0); readB(0, 0);
    stageH(0, base + 1, 1);
    PH_SYNC(); mfmaQ(0, 0); PH_END();
    readB(0, 1);
    stageH(1, base + 1, 1);
    PH_SYNC(); mfmaQ(0, 1); PH_END();
    readA(0, 1);
    stageH(1, base + 2, 0);
    PH_SYNC(); mfmaQ(1, 1); PH_END();
    stageH(0, base + 2, 0);
    PH_SYNC(); mfmaQ(1, 0);
    asm volatile("s_waitcnt vmcnt(4)" ::: "memory");
    PH_END();
    readA(1, 0); readB(1, 0);
    stageH(0, base + 2, 1);
    PH_SYNC(); mfmaQ(0, 0); PH_END();
    readB(1, 1);
    stageH(1, base + 2, 1);
    PH_SYNC(); mfmaQ(0, 1); PH_END();
    readA(1, 1);
    stageH(1, base + 3, 0);
    PH_SYNC(); mfmaQ(1, 1); PH_END();
    stageH(0, base + 3, 0);
    PH_SYNC(); mfmaQ(1, 0);
    asm volatile("s_waitcnt vmcnt(4)" ::: "memory");
    PH_END();
  }

#undef PH_SYNC
#undef PH_END

  bool doRope = (EPI == 0) && (n0 < 6144);
#pragma unroll
  for (int m = 0; m < 8; ++m)
#pragma unroll
    for (int jj = 0; jj < 4; ++jj) {
      int row = m0 + wm * 128 + m * 16 + l4 * 4 + jj;
      int s2 = row & 2047;
#pragma unroll
      for (int j = 0; j < 2; ++j) {
        float lo = acc[m][j][jj];
        float hi = acc[m][2 + j][jj];
        int cl = wn * 32 + j * 16 + l15;
        if (EPI == 0) {
          if (doRope) {
            int d = cl;
            float co = cosT[s2 * 128 + d];
            float si = sinT[s2 * 128 + d];
            float o0 = lo * co - hi * si;
            float o1 = hi * co + lo * si;
            lo = o0; hi = o1;
          }
          U16* cp = (U16*)Cv + (long)row * N + n0 + cl;
          cp[0] = f2bf(lo);
          cp[128] = f2bf(hi);
        } else {
          float* cp = (float*)Cv + (long)row * N + n0 + cl;
          cp[0] = lo;
          cp[128] = hi;
        }
      }
    }
}

// ---------------- banded GQA attention (v9 = v6 + chunk-XOR swizzle) --------
// r13's measured-best structure (256 thr, 64 q-rows); same XOR swizzle as
// gemm applied to K/V staging source + reads (coalescing preserved, 2-way
// read conflicts). Fragment bits per lane unchanged -> bitwise identical.
__global__ __launch_bounds__(256) void k_attn(const U16* __restrict__ QKV,
                                              const U16* __restrict__ VT,
                                              U16* __restrict__ O) {
  __shared__ __align__(16) U16 Ks[2][32 * 256];
  __shared__ __align__(16) U16 Vs[2][256 * 32];
  __shared__ __align__(16) U16 Plds[4][16 * 40];
  int t = threadIdx.x, lane = t & 63, w = t >> 6;
  int flat = blockIdx.x + 32 * (blockIdx.y + 16 * blockIdx.z);
  int l = (flat & 7) * 128 + (flat >> 3);
  int qb = l & 31, h = (l >> 5) & 15, b = l >> 9;
  int s0 = qb * 64;
  int kvh = h >> 1;
  long rowOff = (long)b * 2048 * 8192;
  const U16* Qb = QKV + rowOff + h * 256;
  const U16* Kb = QKV + rowOff + 4096 + kvh * 256;
  const U16* VTb = VT + (long)(b * 8 + kvh) * 64 * 8192;

  int l15 = lane & 15, l4 = lane >> 4;
  int lofs = ((lane & 15) * 4 + ((lane >> 4) ^ ((lane >> 1) & 3))) * 16;

  bf16x8 qf[8];
  {
    const U16* qp = Qb + (long)(s0 + w * 16 + l15) * 8192 + l4 * 8;
#pragma unroll
    for (int kc = 0; kc < 8; ++kc) qf[kc] = *(const bf16x8*)(qp + kc * 32);
  }
  asm volatile("s_waitcnt vmcnt(0)" ::: "memory");

  f32x4 acc[16] = {};
  float mrun = -1e30f, lrun = 0.0f;
  int qpos = s0 + w * 16 + l15;
  int qlo = s0 + w * 16, qhi = qlo + 15;

  int kstart = s0 - 1024; if (kstart < 0) kstart = 0;
  int kend = s0 + 64 + 1024; if (kend > 2048) kend = 2048;

  // staging source (coalesced + chunk-XOR): row (t>>2)&15, chunk (t&3)^((t>>3)&3)
  int sl15 = (t >> 2) & 15, sl4x = (t & 3) ^ ((t >> 3) & 3);
  int offK[4], offV[4];
#pragma unroll
  for (int i = 0; i < 4; ++i) {
    int f = i * 4 + w;
    offK[i] = ((f >> 3) * 16 + sl15) * 8192 + (f & 7) * 32 + sl4x * 8;
    offV[i] = (f * 16 + sl15) * 32 + sl4x * 8;
  }

  const U16* kb = Kb + (long)kstart * 8192;
  const U16* vt0 = VTb + (long)(kstart >> 5) * 8192;

  auto stage = [&](int buf) {
#pragma unroll
    for (int i = 0; i < 4; ++i)
      gload_lds16(kb + offK[i], (char*)&Ks[buf][0] + i * 4096 + w * 1024);
#pragma unroll
    for (int i = 0; i < 4; ++i)
      gload_lds16(vt0 + offV[i], (char*)&Vs[buf][0] + i * 4096 + w * 1024);
    kb += (long)32 * 8192;
    vt0 += 8192;
  };

  auto compute = [&](int buf, int k0) {
    f32x4 sAcc[2] = {};
    const char* Kc = (const char*)&Ks[buf][0] + lofs;
    __builtin_amdgcn_s_setprio(1);
#pragma unroll
    for (int kc = 0; kc < 8; ++kc) {
      bf16x8 a0 = *(const bf16x8*)(Kc + kc * 1024);
      bf16x8 a1 = *(const bf16x8*)(Kc + (8 + kc) * 1024);
      sAcc[0] = __builtin_amdgcn_mfma_f32_16x16x32_bf16(a0, qf[kc], sAcc[0], 0, 0, 0);
      sAcc[1] = __builtin_amdgcn_mfma_f32_16x16x32_bf16(a1, qf[kc], sAcc[1], 0, 0, 0);
    }
    __builtin_amdgcn_s_setprio(0);
    float sv[8];
#pragma unroll
    for (int mp = 0; mp < 2; ++mp)
#pragma unroll
      for (int jj = 0; jj < 4; ++jj) {
        float ex = __expf(sAcc[mp][jj] * 0.0025f);
        sv[mp * 4 + jj] = fmaf(-100.0f, __builtin_amdgcn_rcpf(ex + 1.0f), 50.0f);
      }
    bool full = ((qhi - k0) <= 1024) && ((k0 + 31 - qlo) <= 1024);
    if (!full) {
#pragma unroll
      for (int mp = 0; mp < 2; ++mp)
#pragma unroll
        for (int jj = 0; jj < 4; ++jj) {
          int key = k0 + mp * 16 + l4 * 4 + jj;
          int dd = qpos - key;
          if (dd < -1024 || dd > 1024) sv[mp * 4 + jj] = -3e38f;
        }
    }
    float tmax = sv[0];
#pragma unroll
    for (int i = 1; i < 8; ++i) tmax = fmaxf(tmax, sv[i]);
    tmax = fmaxf(tmax, __shfl_xor(tmax, 16));
    tmax = fmaxf(tmax, __shfl_xor(tmax, 32));
    bool skipall = __all((tmax <= mrun + 8.0f) ? 1 : 0) != 0;
    float mnew = skipall ? mrun : fmaxf(mrun, tmax);
    float pex[8];
    float psum = 0.0f;
#pragma unroll
    for (int i = 0; i < 8; ++i) { pex[i] = __expf(sv[i] - mnew); psum += pex[i]; }
    psum += __shfl_xor(psum, 16);
    psum += __shfl_xor(psum, 32);
    if (skipall) {
      lrun += psum;
    } else {
      float esc = __expf(mrun - mnew);
      f32x4 ev;
#pragma unroll
      for (int jj = 0; jj < 4; ++jj) ev[jj] = __shfl(esc, l4 * 4 + jj);
#pragma unroll
      for (int n = 0; n < 16; ++n) acc[n] *= ev;
      lrun = lrun * esc + psum;
      mrun = mnew;
    }
#pragma unroll
    for (int mp = 0; mp < 2; ++mp)
#pragma unroll
      for (int j2 = 0; j2 < 2; ++j2) {
        unsigned lo = f2bf(pex[mp * 4 + j2 * 2]);
        unsigned hi = f2bf(pex[mp * 4 + j2 * 2 + 1]);
        *(unsigned*)&Plds[w][l15 * 40 + mp * 16 + l4 * 4 + j2 * 2] = lo | (hi << 16);
      }
    asm volatile("s_waitcnt lgkmcnt(0)" ::: "memory");
    __builtin_amdgcn_sched_barrier(0);
    bf16x8 pa = *(const bf16x8*)&Plds[w][l15 * 40 + l4 * 8];
    const char* Vc = (const char*)&Vs[buf][0] + lofs;
    __builtin_amdgcn_s_setprio(1);
#pragma unroll
    for (int n = 0; n < 16; ++n) {
      bf16x8 vb = *(const bf16x8*)(Vc + n * 1024);
      acc[n] = __builtin_amdgcn_mfma_f32_16x16x32_bf16(pa, vb, acc[n], 0, 0, 0);
    }
    __builtin_amdgcn_s_setprio(0);
  };

  int cur = 0;
  stage(0);
  for (int k0 = kstart; k0 < kend - 32; k0 += 32) {
    stage(cur ^ 1);
    asm volatile("s_waitcnt vmcnt(8)" ::: "memory");
    __builtin_amdgcn_s_barrier();
    __builtin_amdgcn_sched_barrier(0);
    compute(cur, k0);
    __builtin_amdgcn_s_barrier();
    cur ^= 1;
  }
  asm volatile("s_waitcnt vmcnt(0)" ::: "memory");
  __builtin_amdgcn_s_barrier();
  __builtin_amdgcn_sched_barrier(0);
  compute(cur, kend - 32);

  f32x4 linv;
#pragma unroll
  for (int jj = 0; jj < 4; ++jj) linv[jj] = 1.0f / __shfl(lrun, l4 * 4 + jj);
#pragma unroll
  for (int jj = 0; jj < 4; ++jj) {
    int row = s0 + w * 16 + l4 * 4 + jj;
    U16* op = O + ((long)b * 2048 + row) * 4096 + h * 256 + l15;
#pragma unroll
    for (int n = 0; n < 16; ++n) op[n * 16] = f2bf(acc[n][jj] * linv[jj]);
  }
}

// ----------------------------------------------------------------------------
extern "C" void kernel_launch(void* const* d_in, const int* in_sizes, int n_in,
                              void* d_out, int out_size, void* d_ws, size_t ws_size,
                              hipStream_t stream) {
  if (n_in < 5) return;
  const float* hid = (const float*)d_in[0];
  const float* Wq  = (const float*)d_in[1];
  const float* Wk  = (const float*)d_in[2];
  const float* Wv  = (const float*)d_in[3];
  const float* Wo  = (const float*)d_in[4];

  char* ws = (char*)d_ws;
  size_t off = 0;
  auto alloc = [&](size_t bytes) {
    char* p = ws + off;
    off += (bytes + 255) & ~(size_t)255;
    return p;
  };
  float* cosT = (float*)alloc((size_t)2048 * 128 * 4);
  float* sinT = (float*)alloc((size_t)2048 * 128 * 4);
  U16*   Xb   = (U16*)alloc((size_t)4096 * 3584 * 2);   // reused: VT, then Wot
  U16*   Wt   = (U16*)alloc((size_t)8192 * 3584 * 2);   // reused: AttO
  U16*   QKV  = (U16*)alloc((size_t)4096 * 8192 * 2);
  if (off > ws_size) return;
  U16* VT   = Xb;
  U16* Wot  = Xb;
  U16* AttO = Wt;

  k_convert<<<7168, 256, 0, stream>>>(hid, Xb, (long)4096 * 3584);
  k_transpose<<<dim3(128, 112), 256, 0, stream>>>(Wq, Wt, 3584, 4096);
  k_transpose<<<dim3(64, 112), 256, 0, stream>>>(Wk, Wt + (size_t)4096 * 3584, 3584, 2048);
  k_transpose<<<dim3(64, 112), 256, 0, stream>>>(Wv, Wt + (size_t)6144 * 3584, 3584, 2048);
  k_rope_tables<<<1024, 256, 0, stream>>>(cosT, sinT);
  k_gemm8<0><<<dim3(32, 16), 512, 0, stream>>>(Xb, Wt, QKV, cosT, sinT, 4096, 8192, 3584);
  k_vtrans<<<dim3(64, 8, 16), 256, 0, stream>>>(QKV, VT);
  k_attn<<<dim3(32, 16, 2), 256, 0, stream>>>(QKV, VT, AttO);
  k_transpose<<<dim3(112, 128), 256, 0, stream>>>(Wo, Wot, 4096, 3584);
  k_gemm8<1><<<dim3(14, 16), 512, 0, stream>>>(AttO, Wot, d_out, cosT, sinT, 4096, 3584, 4096);
}

// Round 17
// 628.638 us; speedup vs baseline: 1.1859x; 1.0008x over previous
//
#include <hip/hip_runtime.h>
#include <stdint.h>

typedef unsigned short U16;
typedef float f32x4 __attribute__((ext_vector_type(4)));
typedef __bf16 bf16x8 __attribute__((ext_vector_type(8)));

static __device__ __forceinline__ U16 f2bf(float x) {
  union { float f; unsigned u; } v; v.f = x;
  unsigned r = v.u + 0x7FFFu + ((v.u >> 16) & 1u);
  return (U16)(r >> 16);
}
static __device__ __forceinline__ float bf2f(U16 h) {
  union { unsigned u; float f; } v; v.u = ((unsigned)h) << 16;
  return v.f;
}

static __device__ __forceinline__ void gload_lds16(const void* g, void* l) {
  __builtin_amdgcn_global_load_lds(
      (const __attribute__((address_space(1))) void*)g,
      (__attribute__((address_space(3))) void*)l, 16, 0, 0);
}

#define SBAR() __builtin_amdgcn_sched_barrier(0)

// ---------------- hidden (fp32) -> bf16 -------------------------------------
__global__ __launch_bounds__(256) void k_convert(const float* __restrict__ src,
                                                 U16* __restrict__ dst, long n) {
  long base = ((long)blockIdx.x * 256 + threadIdx.x) * 8;
  if (base >= n) return;
  const float4* s = (const float4*)(src + base);
  float4 a = s[0], b = s[1];
  U16 o[8] = { f2bf(a.x), f2bf(a.y), f2bf(a.z), f2bf(a.w),
               f2bf(b.x), f2bf(b.y), f2bf(b.z), f2bf(b.w) };
  *(uint4*)(dst + base) = *(const uint4*)o;
}

// ------- W[K][N] (fp32) -> Wt[N][K] bf16, vectorized (32k x 128n tiles) -----
// Read: float4/lane (512B per 32 lanes); write: uint4/lane, 64B-contiguous
// per 4 lanes, consecutive n rows contiguous. Values identical to v1.
__global__ __launch_bounds__(256) void k_transpose(const float* __restrict__ src,
                                                   U16* __restrict__ dst,
                                                   int K, int N) {
  __shared__ U16 tile[32][132];
  int n0 = blockIdx.x * 128, k0 = blockIdx.y * 32;
  int t = threadIdx.x;
  int tx = t & 31, ty = t >> 5;
#pragma unroll
  for (int r = 0; r < 4; ++r) {
    int k = ty + r * 8;
    float4 v = *(const float4*)(src + (long)(k0 + k) * N + n0 + tx * 4);
    U16* tp = &tile[k][tx * 4];
    tp[0] = f2bf(v.x); tp[1] = f2bf(v.y); tp[2] = f2bf(v.z); tp[3] = f2bf(v.w);
  }
  __syncthreads();
  int k8 = (t & 3) * 8;
#pragma unroll
  for (int r = 0; r < 2; ++r) {
    int n = r * 64 + (t >> 2);
    U16 o[8];
#pragma unroll
    for (int i = 0; i < 8; ++i) o[i] = tile[k8 + i][n];
    *(uint4*)(dst + (long)(n0 + n) * K + k0 + k8) = *(const uint4*)o;
  }
}

// ---- V section of QKV -> VT tiled [bk][sTile=64][d=256][s32=32], vectorized -
// One block per 32-key slab covers all 256 d. uint4 reads (512B/row per 32
// lanes) and uint4 writes (contiguous 16KB span per pass). Layout unchanged.
__global__ __launch_bounds__(256) void k_vtrans(const U16* __restrict__ QKV,
                                                U16* __restrict__ VT) {
  __shared__ U16 tile[32][264];
  int s0 = blockIdx.x * 32, bk = blockIdx.z;
  int b = bk >> 3, kvh = bk & 7;
  int t = threadIdx.x;
  const U16* src = QKV + (long)(b * 2048) * 8192 + 6144 + kvh * 256;
  int tx = t & 31, ty = t >> 5;
#pragma unroll
  for (int r = 0; r < 4; ++r) {
    int s = ty + r * 8;
    *(uint4*)&tile[s][tx * 8] = *(const uint4*)(src + (long)(s0 + s) * 8192 + tx * 8);
  }
  __syncthreads();
  long tbase = ((long)bk * 64 + (s0 >> 5)) * 8192;
  int s8 = (t & 3) * 8;
#pragma unroll
  for (int r = 0; r < 4; ++r) {
    int d = r * 64 + (t >> 2);
    U16 o[8];
#pragma unroll
    for (int i = 0; i < 8; ++i) o[i] = tile[s8 + i][d];
    *(uint4*)(VT + tbase + d * 32 + s8) = *(const uint4*)o;
  }
}

// ---------------- RoPE tables (fp32) ----------------------------------------
__global__ __launch_bounds__(256) void k_rope_tables(float* __restrict__ cosT,
                                                     float* __restrict__ sinT) {
  int i = blockIdx.x * 256 + threadIdx.x;
  int s = i >> 7, d = i & 127;
  float freq = expf(-9.210340371976184f * (float)d / 128.0f);
  float ang = (float)s * freq;
  cosT[i] = cosf(ang);
  sinT[i] = sinf(ang);
}

// ---------------- GEMM v8 (r16, unchanged): chunk-XOR swizzle, 8-PHASE ------
template <int EPI>
__global__ __launch_bounds__(512, 1) void k_gemm8(const U16* __restrict__ A,
                                                  const U16* __restrict__ Bt,
                                                  void* __restrict__ Cv,
                                                  const float* __restrict__ cosT,
                                                  const float* __restrict__ sinT,
                                                  int M, int N, int K) {
  __shared__ __align__(16) U16 Asl[2][2][128 * 64];
  __shared__ __align__(16) U16 Bsl[2][2][128 * 64];
  int nwg = gridDim.x * gridDim.y;
  int flat = blockIdx.y * gridDim.x + blockIdx.x;
  int cpx = nwg >> 3;
  int swz = (flat & 7) * cpx + (flat >> 3);
  int bx = swz % gridDim.x, by = swz / gridDim.x;
  int t = threadIdx.x, lane = t & 63, w = t >> 6;
  int m0 = by * 256, n0 = bx * 256;
  int wm = w >> 2, wn = w & 3;
  int l15 = lane & 15, l4 = lane >> 4;
  int lofs = ((lane & 15) * 4 + ((lane >> 4) ^ ((lane >> 1) & 3))) * 16;

  f32x4 acc[8][4] = {};
  int T = K >> 6;

  int sr = lane >> 2, sc4 = ((lane & 3) ^ ((lane >> 3) & 3)) * 8;
  int fA0 = (w >> 1) * 16 + sr, kA0 = (w & 1) * 32 + sc4;
  int fA1 = ((8 + w) >> 1) * 16 + sr, kA1 = ((8 + w) & 1) * 32 + sc4;
  const U16* aj0 = A + (long)(m0 + fA0) * K + kA0;
  const U16* aj1 = A + (long)(m0 + fA1) * K + kA1;
  const U16* bj0 = Bt + (long)(n0 + fA0) * K + kA0;
  const U16* bj1 = Bt + (long)(n0 + fA1) * K + kA1;

  auto stageH = [&](int op, int kt, int h) {
    int buf = kt & 1;
    int ktc = (kt < T) ? kt : 0;
    long off = (long)ktc * 64 + (long)h * 128 * K;
    if (op == 0) {
      gload_lds16(aj0 + off, (char*)&Asl[buf][h][0] + w * 1024);
      gload_lds16(aj1 + off, (char*)&Asl[buf][h][0] + 8192 + w * 1024);
    } else {
      gload_lds16(bj0 + off, (char*)&Bsl[buf][h][0] + w * 1024);
      gload_lds16(bj1 + off, (char*)&Bsl[buf][h][0] + 8192 + w * 1024);
    }
  };

  bf16x8 Ar[4][2], Bq[2][2][2];

  auto readA = [&](int buf, int r) {
    const char* base = (const char*)&Asl[buf][wm][0] + lofs;
#pragma unroll
    for (int i = 0; i < 4; ++i)
#pragma unroll
      for (int kk = 0; kk < 2; ++kk)
        Ar[i][kk] = *(const bf16x8*)(base + ((r * 4 + i) * 2 + kk) * 1024);
  };
  auto readB = [&](int buf, int c) {
    const char* base = (const char*)&Bsl[buf][c][0] + lofs;
#pragma unroll
    for (int j = 0; j < 2; ++j)
#pragma unroll
      for (int kk = 0; kk < 2; ++kk)
        Bq[c][j][kk] = *(const bf16x8*)(base + ((2 * wn + j) * 2 + kk) * 1024);
  };
  auto mfmaQ = [&](int r, int c) {
    __builtin_amdgcn_s_setprio(1);
#pragma unroll
    for (int i = 0; i < 4; ++i)
#pragma unroll
      for (int j = 0; j < 2; ++j) {
        int m = r * 4 + i, n = c * 2 + j;
        acc[m][n] = __builtin_amdgcn_mfma_f32_16x16x32_bf16(Ar[i][0], Bq[c][j][0], acc[m][n], 0, 0, 0);
        acc[m][n] = __builtin_amdgcn_mfma_f32_16x16x32_bf16(Ar[i][1], Bq[c][j][1], acc[m][n], 0, 0, 0);
      }
    __builtin_amdgcn_s_setprio(0);
  };

#define PH_SYNC() do { SBAR(); __builtin_amdgcn_s_barrier(); \
    asm volatile("s_waitcnt lgkmcnt(0)" ::: "memory"); SBAR(); } while (0)
#define PH_END() do { SBAR(); __builtin_amdgcn_s_barrier(); SBAR(); } while (0)

  stageH(0, 0, 0); stageH(0, 0, 1); stageH(1, 0, 0); stageH(1, 0, 1);
  stageH(1, 1, 0); stageH(0, 1, 0);
  asm volatile("s_waitcnt vmcnt(4)" ::: "memory");
  SBAR(); __builtin_amdgcn_s_barrier(); SBAR();

  for (int base = 0; base < T; base += 2) {
    readA(0, 0); readB(0, 0);
    stageH(0, base + 1, 1);
    PH_SYNC(); mfmaQ(0, 0); PH_END();
    readB(0, 1);
    stageH(1, base + 1, 1);
    PH_SYNC(); mfmaQ(0, 1); PH_END();
    readA(0, 1);
    stageH(1, base + 2, 0);
    PH_SYNC(); mfmaQ(1, 1); PH_END();
    stageH(0, base + 2, 0);
    PH_SYNC(); mfmaQ(1, 0);
    asm volatile("s_waitcnt vmcnt(4)" ::: "memory");
    PH_END();
    readA(1, 0); readB(1, 0);
    stageH(0, base + 2, 1);
    PH_SYNC(); mfmaQ(0, 0); PH_END();
    readB(1, 1);
    stageH(1, base + 2, 1);
    PH_SYNC(); mfmaQ(0, 1); PH_END();
    readA(1, 1);
    stageH(1, base + 3, 0);
    PH_SYNC(); mfmaQ(1, 1); PH_END();
    stageH(0, base + 3, 0);
    PH_SYNC(); mfmaQ(1, 0);
    asm volatile("s_waitcnt vmcnt(4)" ::: "memory");
    PH_END();
  }

#undef PH_SYNC
#undef PH_END

  bool doRope = (EPI == 0) && (n0 < 6144);
#pragma unroll
  for (int m = 0; m < 8; ++m)
#pragma unroll
    for (int jj = 0; jj < 4; ++jj) {
      int row = m0 + wm * 128 + m * 16 + l4 * 4 + jj;
      int s2 = row & 2047;
#pragma unroll
      for (int j = 0; j < 2; ++j) {
        float lo = acc[m][j][jj];
        float hi = acc[m][2 + j][jj];
        int cl = wn * 32 + j * 16 + l15;
        if (EPI == 0) {
          if (doRope) {
            int d = cl;
            float co = cosT[s2 * 128 + d];
            float si = sinT[s2 * 128 + d];
            float o0 = lo * co - hi * si;
            float o1 = hi * co + lo * si;
            lo = o0; hi = o1;
          }
          U16* cp = (U16*)Cv + (long)row * N + n0 + cl;
          cp[0] = f2bf(lo);
          cp[128] = f2bf(hi);
        } else {
          float* cp = (float*)Cv + (long)row * N + n0 + cl;
          cp[0] = lo;
          cp[128] = hi;
        }
      }
    }
}

// ---------------- banded GQA attention (v9, r16 unchanged) ------------------
__global__ __launch_bounds__(256) void k_attn(const U16* __restrict__ QKV,
                                              const U16* __restrict__ VT,
                                              U16* __restrict__ O) {
  __shared__ __align__(16) U16 Ks[2][32 * 256];
  __shared__ __align__(16) U16 Vs[2][256 * 32];
  __shared__ __align__(16) U16 Plds[4][16 * 40];
  int t = threadIdx.x, lane = t & 63, w = t >> 6;
  int flat = blockIdx.x + 32 * (blockIdx.y + 16 * blockIdx.z);
  int l = (flat & 7) * 128 + (flat >> 3);
  int qb = l & 31, h = (l >> 5) & 15, b = l >> 9;
  int s0 = qb * 64;
  int kvh = h >> 1;
  long rowOff = (long)b * 2048 * 8192;
  const U16* Qb = QKV + rowOff + h * 256;
  const U16* Kb = QKV + rowOff + 4096 + kvh * 256;
  const U16* VTb = VT + (long)(b * 8 + kvh) * 64 * 8192;

  int l15 = lane & 15, l4 = lane >> 4;
  int lofs = ((lane & 15) * 4 + ((lane >> 4) ^ ((lane >> 1) & 3))) * 16;

  bf16x8 qf[8];
  {
    const U16* qp = Qb + (long)(s0 + w * 16 + l15) * 8192 + l4 * 8;
#pragma unroll
    for (int kc = 0; kc < 8; ++kc) qf[kc] = *(const bf16x8*)(qp + kc * 32);
  }
  asm volatile("s_waitcnt vmcnt(0)" ::: "memory");

  f32x4 acc[16] = {};
  float mrun = -1e30f, lrun = 0.0f;
  int qpos = s0 + w * 16 + l15;
  int qlo = s0 + w * 16, qhi = qlo + 15;

  int kstart = s0 - 1024; if (kstart < 0) kstart = 0;
  int kend = s0 + 64 + 1024; if (kend > 2048) kend = 2048;

  int sl15 = (t >> 2) & 15, sl4x = (t & 3) ^ ((t >> 3) & 3);
  int offK[4], offV[4];
#pragma unroll
  for (int i = 0; i < 4; ++i) {
    int f = i * 4 + w;
    offK[i] = ((f >> 3) * 16 + sl15) * 8192 + (f & 7) * 32 + sl4x * 8;
    offV[i] = (f * 16 + sl15) * 32 + sl4x * 8;
  }

  const U16* kb = Kb + (long)kstart * 8192;
  const U16* vt0 = VTb + (long)(kstart >> 5) * 8192;

  auto stage = [&](int buf) {
#pragma unroll
    for (int i = 0; i < 4; ++i)
      gload_lds16(kb + offK[i], (char*)&Ks[buf][0] + i * 4096 + w * 1024);
#pragma unroll
    for (int i = 0; i < 4; ++i)
      gload_lds16(vt0 + offV[i], (char*)&Vs[buf][0] + i * 4096 + w * 1024);
    kb += (long)32 * 8192;
    vt0 += 8192;
  };

  auto compute = [&](int buf, int k0) {
    f32x4 sAcc[2] = {};
    const char* Kc = (const char*)&Ks[buf][0] + lofs;
    __builtin_amdgcn_s_setprio(1);
#pragma unroll
    for (int kc = 0; kc < 8; ++kc) {
      bf16x8 a0 = *(const bf16x8*)(Kc + kc * 1024);
      bf16x8 a1 = *(const bf16x8*)(Kc + (8 + kc) * 1024);
      sAcc[0] = __builtin_amdgcn_mfma_f32_16x16x32_bf16(a0, qf[kc], sAcc[0], 0, 0, 0);
      sAcc[1] = __builtin_amdgcn_mfma_f32_16x16x32_bf16(a1, qf[kc], sAcc[1], 0, 0, 0);
    }
    __builtin_amdgcn_s_setprio(0);
    float sv[8];
#pragma unroll
    for (int mp = 0; mp < 2; ++mp)
#pragma unroll
      for (int jj = 0; jj < 4; ++jj) {
        float ex = __expf(sAcc[mp][jj] * 0.0025f);
        sv[mp * 4 + jj] = fmaf(-100.0f, __builtin_amdgcn_rcpf(ex + 1.0f), 50.0f);
      }
    bool full = ((qhi - k0) <= 1024) && ((k0 + 31 - qlo) <= 1024);
    if (!full) {
#pragma unroll
      for (int mp = 0; mp < 2; ++mp)
#pragma unroll
        for (int jj = 0; jj < 4; ++jj) {
          int key = k0 + mp * 16 + l4 * 4 + jj;
          int dd = qpos - key;
          if (dd < -1024 || dd > 1024) sv[mp * 4 + jj] = -3e38f;
        }
    }
    float tmax = sv[0];
#pragma unroll
    for (int i = 1; i < 8; ++i) tmax = fmaxf(tmax, sv[i]);
    tmax = fmaxf(tmax, __shfl_xor(tmax, 16));
    tmax = fmaxf(tmax, __shfl_xor(tmax, 32));
    bool skipall = __all((tmax <= mrun + 8.0f) ? 1 : 0) != 0;
    float mnew = skipall ? mrun : fmaxf(mrun, tmax);
    float pex[8];
    float psum = 0.0f;
#pragma unroll
    for (int i = 0; i < 8; ++i) { pex[i] = __expf(sv[i] - mnew); psum += pex[i]; }
    psum += __shfl_xor(psum, 16);
    psum += __shfl_xor(psum, 32);
    if (skipall) {
      lrun += psum;
    } else {
      float esc = __expf(mrun - mnew);
      f32x4 ev;
#pragma unroll
      for (int jj = 0; jj < 4; ++jj) ev[jj] = __shfl(esc, l4 * 4 + jj);
#pragma unroll
      for (int n = 0; n < 16; ++n) acc[n] *= ev;
      lrun = lrun * esc + psum;
      mrun = mnew;
    }
#pragma unroll
    for (int mp = 0; mp < 2; ++mp)
#pragma unroll
      for (int j2 = 0; j2 < 2; ++j2) {
        unsigned lo = f2bf(pex[mp * 4 + j2 * 2]);
        unsigned hi = f2bf(pex[mp * 4 + j2 * 2 + 1]);
        *(unsigned*)&Plds[w][l15 * 40 + mp * 16 + l4 * 4 + j2 * 2] = lo | (hi << 16);
      }
    asm volatile("s_waitcnt lgkmcnt(0)" ::: "memory");
    __builtin_amdgcn_sched_barrier(0);
    bf16x8 pa = *(const bf16x8*)&Plds[w][l15 * 40 + l4 * 8];
    const char* Vc = (const char*)&Vs[buf][0] + lofs;
    __builtin_amdgcn_s_setprio(1);
#pragma unroll
    for (int n = 0; n < 16; ++n) {
      bf16x8 vb = *(const bf16x8*)(Vc + n * 1024);
      acc[n] = __builtin_amdgcn_mfma_f32_16x16x32_bf16(pa, vb, acc[n], 0, 0, 0);
    }
    __builtin_amdgcn_s_setprio(0);
  };

  int cur = 0;
  stage(0);
  for (int k0 = kstart; k0 < kend - 32; k0 += 32) {
    stage(cur ^ 1);
    asm volatile("s_waitcnt vmcnt(8)" ::: "memory");
    __builtin_amdgcn_s_barrier();
    __builtin_amdgcn_sched_barrier(0);
    compute(cur, k0);
    __builtin_amdgcn_s_barrier();
    cur ^= 1;
  }
  asm volatile("s_waitcnt vmcnt(0)" ::: "memory");
  __builtin_amdgcn_s_barrier();
  __builtin_amdgcn_sched_barrier(0);
  compute(cur, kend - 32);

  f32x4 linv;
#pragma unroll
  for (int jj = 0; jj < 4; ++jj) linv[jj] = 1.0f / __shfl(lrun, l4 * 4 + jj);
#pragma unroll
  for (int jj = 0; jj < 4; ++jj) {
    int row = s0 + w * 16 + l4 * 4 + jj;
    U16* op = O + ((long)b * 2048 + row) * 4096 + h * 256 + l15;
#pragma unroll
    for (int n = 0; n < 16; ++n) op[n * 16] = f2bf(acc[n][jj] * linv[jj]);
  }
}

// ----------------------------------------------------------------------------
extern "C" void kernel_launch(void* const* d_in, const int* in_sizes, int n_in,
                              void* d_out, int out_size, void* d_ws, size_t ws_size,
                              hipStream_t stream) {
  if (n_in < 5) return;
  const float* hid = (const float*)d_in[0];
  const float* Wq  = (const float*)d_in[1];
  const float* Wk  = (const float*)d_in[2];
  const float* Wv  = (const float*)d_in[3];
  const float* Wo  = (const float*)d_in[4];

  char* ws = (char*)d_ws;
  size_t off = 0;
  auto alloc = [&](size_t bytes) {
    char* p = ws + off;
    off += (bytes + 255) & ~(size_t)255;
    return p;
  };
  float* cosT = (float*)alloc((size_t)2048 * 128 * 4);
  float* sinT = (float*)alloc((size_t)2048 * 128 * 4);
  U16*   Xb   = (U16*)alloc((size_t)4096 * 3584 * 2);   // reused: VT, then Wot
  U16*   Wt   = (U16*)alloc((size_t)8192 * 3584 * 2);   // reused: AttO
  U16*   QKV  = (U16*)alloc((size_t)4096 * 8192 * 2);
  if (off > ws_size) return;
  U16* VT   = Xb;
  U16* Wot  = Xb;
  U16* AttO = Wt;

  k_convert<<<7168, 256, 0, stream>>>(hid, Xb, (long)4096 * 3584);
  k_transpose<<<dim3(32, 112), 256, 0, stream>>>(Wq, Wt, 3584, 4096);
  k_transpose<<<dim3(16, 112), 256, 0, stream>>>(Wk, Wt + (size_t)4096 * 3584, 3584, 2048);
  k_transpose<<<dim3(16, 112), 256, 0, stream>>>(Wv, Wt + (size_t)6144 * 3584, 3584, 2048);
  k_rope_tables<<<1024, 256, 0, stream>>>(cosT, sinT);
  k_gemm8<0><<<dim3(32, 16), 512, 0, stream>>>(Xb, Wt, QKV, cosT, sinT, 4096, 8192, 3584);
  k_vtrans<<<dim3(64, 1, 16), 256, 0, stream>>>(QKV, VT);
  k_attn<<<dim3(32, 16, 2), 256, 0, stream>>>(QKV, VT, AttO);
  k_transpose<<<dim3(28, 128), 256, 0, stream>>>(Wo, Wot, 4096, 3584);
  k_gemm8<1><<<dim3(14, 16), 512, 0, stream>>>(AttO, Wot, d_out, cosT, sinT, 4096, 3584, 4096);
}

// Round 18
// 619.825 us; speedup vs baseline: 1.2028x; 1.0142x over previous
//
#include <hip/hip_runtime.h>
#include <stdint.h>

typedef unsigned short U16;
typedef float f32x4 __attribute__((ext_vector_type(4)));
typedef __bf16 bf16x8 __attribute__((ext_vector_type(8)));

static __device__ __forceinline__ U16 f2bf(float x) {
  union { float f; unsigned u; } v; v.f = x;
  unsigned r = v.u + 0x7FFFu + ((v.u >> 16) & 1u);
  return (U16)(r >> 16);
}
static __device__ __forceinline__ float bf2f(U16 h) {
  union { unsigned u; float f; } v; v.u = ((unsigned)h) << 16;
  return v.f;
}

static __device__ __forceinline__ void gload_lds16(const void* g, void* l) {
  __builtin_amdgcn_global_load_lds(
      (const __attribute__((address_space(1))) void*)g,
      (__attribute__((address_space(3))) void*)l, 16, 0, 0);
}

#define SBAR() __builtin_amdgcn_sched_barrier(0)

// ---------------- hidden (fp32) -> bf16 -------------------------------------
__global__ __launch_bounds__(256) void k_convert(const float* __restrict__ src,
                                                 U16* __restrict__ dst, long n) {
  long base = ((long)blockIdx.x * 256 + threadIdx.x) * 8;
  if (base >= n) return;
  const float4* s = (const float4*)(src + base);
  float4 a = s[0], b = s[1];
  U16 o[8] = { f2bf(a.x), f2bf(a.y), f2bf(a.z), f2bf(a.w),
               f2bf(b.x), f2bf(b.y), f2bf(b.z), f2bf(b.w) };
  *(uint4*)(dst + base) = *(const uint4*)o;
}

// ------- W[K][N] (fp32) -> Wt[N][K] bf16, vectorized (32k x 128n tiles) -----
__global__ __launch_bounds__(256) void k_transpose(const float* __restrict__ src,
                                                   U16* __restrict__ dst,
                                                   int K, int N) {
  __shared__ U16 tile[32][132];
  int n0 = blockIdx.x * 128, k0 = blockIdx.y * 32;
  int t = threadIdx.x;
  int tx = t & 31, ty = t >> 5;
#pragma unroll
  for (int r = 0; r < 4; ++r) {
    int k = ty + r * 8;
    float4 v = *(const float4*)(src + (long)(k0 + k) * N + n0 + tx * 4);
    U16* tp = &tile[k][tx * 4];
    tp[0] = f2bf(v.x); tp[1] = f2bf(v.y); tp[2] = f2bf(v.z); tp[3] = f2bf(v.w);
  }
  __syncthreads();
  int k8 = (t & 3) * 8;
#pragma unroll
  for (int r = 0; r < 2; ++r) {
    int n = r * 64 + (t >> 2);
    U16 o[8];
#pragma unroll
    for (int i = 0; i < 8; ++i) o[i] = tile[k8 + i][n];
    *(uint4*)(dst + (long)(n0 + n) * K + k0 + k8) = *(const uint4*)o;
  }
}

// ---- V section of QKV -> VT tiled [bk][sTile=64][d=256][s32=32], vectorized -
__global__ __launch_bounds__(256) void k_vtrans(const U16* __restrict__ QKV,
                                                U16* __restrict__ VT) {
  __shared__ U16 tile[32][264];
  int s0 = blockIdx.x * 32, bk = blockIdx.z;
  int b = bk >> 3, kvh = bk & 7;
  int t = threadIdx.x;
  const U16* src = QKV + (long)(b * 2048) * 8192 + 6144 + kvh * 256;
  int tx = t & 31, ty = t >> 5;
#pragma unroll
  for (int r = 0; r < 4; ++r) {
    int s = ty + r * 8;
    *(uint4*)&tile[s][tx * 8] = *(const uint4*)(src + (long)(s0 + s) * 8192 + tx * 8);
  }
  __syncthreads();
  long tbase = ((long)bk * 64 + (s0 >> 5)) * 8192;
  int s8 = (t & 3) * 8;
#pragma unroll
  for (int r = 0; r < 4; ++r) {
    int d = r * 64 + (t >> 2);
    U16 o[8];
#pragma unroll
    for (int i = 0; i < 8; ++i) o[i] = tile[s8 + i][d];
    *(uint4*)(VT + tbase + d * 32 + s8) = *(const uint4*)o;
  }
}

// ---------------- RoPE tables (fp32) ----------------------------------------
__global__ __launch_bounds__(256) void k_rope_tables(float* __restrict__ cosT,
                                                     float* __restrict__ sinT) {
  int i = blockIdx.x * 256 + threadIdx.x;
  int s = i >> 7, d = i & 127;
  float freq = expf(-9.210340371976184f * (float)d / 128.0f);
  float ang = (float)s * freq;
  cosT[i] = cosf(ang);
  sinT[i] = sinf(ang);
}

// ---------------- GEMM v9: 256x256, BK=64, 8-PHASE, relaxed barriers --------
// Change vs v8: per-phase sync is now {reads; stage; lgkmcnt(0); barrier;
// MFMA} with NO trailing barrier (kept only after the vmcnt(4) at P3/P7).
// lgkm BEFORE the barrier => when barrier releases, all waves' reads of that
// phase are COMPLETE, so any later stage-write is safe (ledger: every stage
// target has >=1 intervening phase-barrier after its last reader). Waves may
// skew by one phase => next-phase reads/stage overlap current-phase MFMA.
// Accumulation order unchanged -> bitwise-identical output.
template <int EPI>
__global__ __launch_bounds__(512, 1) void k_gemm8(const U16* __restrict__ A,
                                                  const U16* __restrict__ Bt,
                                                  void* __restrict__ Cv,
                                                  const float* __restrict__ cosT,
                                                  const float* __restrict__ sinT,
                                                  int M, int N, int K) {
  __shared__ __align__(16) U16 Asl[2][2][128 * 64];
  __shared__ __align__(16) U16 Bsl[2][2][128 * 64];
  int nwg = gridDim.x * gridDim.y;
  int flat = blockIdx.y * gridDim.x + blockIdx.x;
  int cpx = nwg >> 3;
  int swz = (flat & 7) * cpx + (flat >> 3);
  int bx = swz % gridDim.x, by = swz / gridDim.x;
  int t = threadIdx.x, lane = t & 63, w = t >> 6;
  int m0 = by * 256, n0 = bx * 256;
  int wm = w >> 2, wn = w & 3;
  int l15 = lane & 15, l4 = lane >> 4;
  int lofs = ((lane & 15) * 4 + ((lane >> 4) ^ ((lane >> 1) & 3))) * 16;

  f32x4 acc[8][4] = {};
  int T = K >> 6;

  int sr = lane >> 2, sc4 = ((lane & 3) ^ ((lane >> 3) & 3)) * 8;
  int fA0 = (w >> 1) * 16 + sr, kA0 = (w & 1) * 32 + sc4;
  int fA1 = ((8 + w) >> 1) * 16 + sr, kA1 = ((8 + w) & 1) * 32 + sc4;
  const U16* aj0 = A + (long)(m0 + fA0) * K + kA0;
  const U16* aj1 = A + (long)(m0 + fA1) * K + kA1;
  const U16* bj0 = Bt + (long)(n0 + fA0) * K + kA0;
  const U16* bj1 = Bt + (long)(n0 + fA1) * K + kA1;

  auto stageH = [&](int op, int kt, int h) {
    int buf = kt & 1;
    int ktc = (kt < T) ? kt : 0;
    long off = (long)ktc * 64 + (long)h * 128 * K;
    if (op == 0) {
      gload_lds16(aj0 + off, (char*)&Asl[buf][h][0] + w * 1024);
      gload_lds16(aj1 + off, (char*)&Asl[buf][h][0] + 8192 + w * 1024);
    } else {
      gload_lds16(bj0 + off, (char*)&Bsl[buf][h][0] + w * 1024);
      gload_lds16(bj1 + off, (char*)&Bsl[buf][h][0] + 8192 + w * 1024);
    }
  };

  bf16x8 Ar[4][2], Bq[2][2][2];

  auto readA = [&](int buf, int r) {
    const char* base = (const char*)&Asl[buf][wm][0] + lofs;
#pragma unroll
    for (int i = 0; i < 4; ++i)
#pragma unroll
      for (int kk = 0; kk < 2; ++kk)
        Ar[i][kk] = *(const bf16x8*)(base + ((r * 4 + i) * 2 + kk) * 1024);
  };
  auto readB = [&](int buf, int c) {
    const char* base = (const char*)&Bsl[buf][c][0] + lofs;
#pragma unroll
    for (int j = 0; j < 2; ++j)
#pragma unroll
      for (int kk = 0; kk < 2; ++kk)
        Bq[c][j][kk] = *(const bf16x8*)(base + ((2 * wn + j) * 2 + kk) * 1024);
  };
  auto mfmaQ = [&](int r, int c) {
    __builtin_amdgcn_s_setprio(1);
#pragma unroll
    for (int i = 0; i < 4; ++i)
#pragma unroll
      for (int j = 0; j < 2; ++j) {
        int m = r * 4 + i, n = c * 2 + j;
        acc[m][n] = __builtin_amdgcn_mfma_f32_16x16x32_bf16(Ar[i][0], Bq[c][j][0], acc[m][n], 0, 0, 0);
        acc[m][n] = __builtin_amdgcn_mfma_f32_16x16x32_bf16(Ar[i][1], Bq[c][j][1], acc[m][n], 0, 0, 0);
      }
    __builtin_amdgcn_s_setprio(0);
  };

  // lgkm BEFORE barrier: on barrier release, all waves' reads are complete.
#define PH_PRE() do { SBAR(); \
    asm volatile("s_waitcnt lgkmcnt(0)" ::: "memory"); SBAR(); \
    __builtin_amdgcn_s_barrier(); SBAR(); } while (0)
#define PH_VM() do { \
    asm volatile("s_waitcnt vmcnt(4)" ::: "memory"); SBAR(); \
    __builtin_amdgcn_s_barrier(); SBAR(); } while (0)

  stageH(0, 0, 0); stageH(0, 0, 1); stageH(1, 0, 0); stageH(1, 0, 1);
  stageH(1, 1, 0); stageH(0, 1, 0);
  asm volatile("s_waitcnt vmcnt(4)" ::: "memory");
  SBAR(); __builtin_amdgcn_s_barrier(); SBAR();

  for (int base = 0; base < T; base += 2) {
    readA(0, 0); readB(0, 0);
    stageH(0, base + 1, 1);
    PH_PRE(); mfmaQ(0, 0);
    readB(0, 1);
    stageH(1, base + 1, 1);
    PH_PRE(); mfmaQ(0, 1);
    readA(0, 1);
    stageH(1, base + 2, 0);
    PH_PRE(); mfmaQ(1, 1);
    stageH(0, base + 2, 0);
    PH_PRE(); mfmaQ(1, 0);
    PH_VM();
    readA(1, 0); readB(1, 0);
    stageH(0, base + 2, 1);
    PH_PRE(); mfmaQ(0, 0);
    readB(1, 1);
    stageH(1, base + 2, 1);
    PH_PRE(); mfmaQ(0, 1);
    readA(1, 1);
    stageH(1, base + 3, 0);
    PH_PRE(); mfmaQ(1, 1);
    stageH(0, base + 3, 0);
    PH_PRE(); mfmaQ(1, 0);
    PH_VM();
  }

#undef PH_PRE
#undef PH_VM

  bool doRope = (EPI == 0) && (n0 < 6144);
#pragma unroll
  for (int m = 0; m < 8; ++m)
#pragma unroll
    for (int jj = 0; jj < 4; ++jj) {
      int row = m0 + wm * 128 + m * 16 + l4 * 4 + jj;
      int s2 = row & 2047;
#pragma unroll
      for (int j = 0; j < 2; ++j) {
        float lo = acc[m][j][jj];
        float hi = acc[m][2 + j][jj];
        int cl = wn * 32 + j * 16 + l15;
        if (EPI == 0) {
          if (doRope) {
            int d = cl;
            float co = cosT[s2 * 128 + d];
            float si = sinT[s2 * 128 + d];
            float o0 = lo * co - hi * si;
            float o1 = hi * co + lo * si;
            lo = o0; hi = o1;
          }
          U16* cp = (U16*)Cv + (long)row * N + n0 + cl;
          cp[0] = f2bf(lo);
          cp[128] = f2bf(hi);
        } else {
          float* cp = (float*)Cv + (long)row * N + n0 + cl;
          cp[0] = lo;
          cp[128] = hi;
        }
      }
    }
}

// ---------------- banded GQA attention (v9, r16 unchanged) ------------------
__global__ __launch_bounds__(256) void k_attn(const U16* __restrict__ QKV,
                                              const U16* __restrict__ VT,
                                              U16* __restrict__ O) {
  __shared__ __align__(16) U16 Ks[2][32 * 256];
  __shared__ __align__(16) U16 Vs[2][256 * 32];
  __shared__ __align__(16) U16 Plds[4][16 * 40];
  int t = threadIdx.x, lane = t & 63, w = t >> 6;
  int flat = blockIdx.x + 32 * (blockIdx.y + 16 * blockIdx.z);
  int l = (flat & 7) * 128 + (flat >> 3);
  int qb = l & 31, h = (l >> 5) & 15, b = l >> 9;
  int s0 = qb * 64;
  int kvh = h >> 1;
  long rowOff = (long)b * 2048 * 8192;
  const U16* Qb = QKV + rowOff + h * 256;
  const U16* Kb = QKV + rowOff + 4096 + kvh * 256;
  const U16* VTb = VT + (long)(b * 8 + kvh) * 64 * 8192;

  int l15 = lane & 15, l4 = lane >> 4;
  int lofs = ((lane & 15) * 4 + ((lane >> 4) ^ ((lane >> 1) & 3))) * 16;

  bf16x8 qf[8];
  {
    const U16* qp = Qb + (long)(s0 + w * 16 + l15) * 8192 + l4 * 8;
#pragma unroll
    for (int kc = 0; kc < 8; ++kc) qf[kc] = *(const bf16x8*)(qp + kc * 32);
  }
  asm volatile("s_waitcnt vmcnt(0)" ::: "memory");

  f32x4 acc[16] = {};
  float mrun = -1e30f, lrun = 0.0f;
  int qpos = s0 + w * 16 + l15;
  int qlo = s0 + w * 16, qhi = qlo + 15;

  int kstart = s0 - 1024; if (kstart < 0) kstart = 0;
  int kend = s0 + 64 + 1024; if (kend > 2048) kend = 2048;

  int sl15 = (t >> 2) & 15, sl4x = (t & 3) ^ ((t >> 3) & 3);
  int offK[4], offV[4];
#pragma unroll
  for (int i = 0; i < 4; ++i) {
    int f = i * 4 + w;
    offK[i] = ((f >> 3) * 16 + sl15) * 8192 + (f & 7) * 32 + sl4x * 8;
    offV[i] = (f * 16 + sl15) * 32 + sl4x * 8;
  }

  const U16* kb = Kb + (long)kstart * 8192;
  const U16* vt0 = VTb + (long)(kstart >> 5) * 8192;

  auto stage = [&](int buf) {
#pragma unroll
    for (int i = 0; i < 4; ++i)
      gload_lds16(kb + offK[i], (char*)&Ks[buf][0] + i * 4096 + w * 1024);
#pragma unroll
    for (int i = 0; i < 4; ++i)
      gload_lds16(vt0 + offV[i], (char*)&Vs[buf][0] + i * 4096 + w * 1024);
    kb += (long)32 * 8192;
    vt0 += 8192;
  };

  auto compute = [&](int buf, int k0) {
    f32x4 sAcc[2] = {};
    const char* Kc = (const char*)&Ks[buf][0] + lofs;
    __builtin_amdgcn_s_setprio(1);
#pragma unroll
    for (int kc = 0; kc < 8; ++kc) {
      bf16x8 a0 = *(const bf16x8*)(Kc + kc * 1024);
      bf16x8 a1 = *(const bf16x8*)(Kc + (8 + kc) * 1024);
      sAcc[0] = __builtin_amdgcn_mfma_f32_16x16x32_bf16(a0, qf[kc], sAcc[0], 0, 0, 0);
      sAcc[1] = __builtin_amdgcn_mfma_f32_16x16x32_bf16(a1, qf[kc], sAcc[1], 0, 0, 0);
    }
    __builtin_amdgcn_s_setprio(0);
    float sv[8];
#pragma unroll
    for (int mp = 0; mp < 2; ++mp)
#pragma unroll
      for (int jj = 0; jj < 4; ++jj) {
        float ex = __expf(sAcc[mp][jj] * 0.0025f);
        sv[mp * 4 + jj] = fmaf(-100.0f, __builtin_amdgcn_rcpf(ex + 1.0f), 50.0f);
      }
    bool full = ((qhi - k0) <= 1024) && ((k0 + 31 - qlo) <= 1024);
    if (!full) {
#pragma unroll
      for (int mp = 0; mp < 2; ++mp)
#pragma unroll
        for (int jj = 0; jj < 4; ++jj) {
          int key = k0 + mp * 16 + l4 * 4 + jj;
          int dd = qpos - key;
          if (dd < -1024 || dd > 1024) sv[mp * 4 + jj] = -3e38f;
        }
    }
    float tmax = sv[0];
#pragma unroll
    for (int i = 1; i < 8; ++i) tmax = fmaxf(tmax, sv[i]);
    tmax = fmaxf(tmax, __shfl_xor(tmax, 16));
    tmax = fmaxf(tmax, __shfl_xor(tmax, 32));
    bool skipall = __all((tmax <= mrun + 8.0f) ? 1 : 0) != 0;
    float mnew = skipall ? mrun : fmaxf(mrun, tmax);
    float pex[8];
    float psum = 0.0f;
#pragma unroll
    for (int i = 0; i < 8; ++i) { pex[i] = __expf(sv[i] - mnew); psum += pex[i]; }
    psum += __shfl_xor(psum, 16);
    psum += __shfl_xor(psum, 32);
    if (skipall) {
      lrun += psum;
    } else {
      float esc = __expf(mrun - mnew);
      f32x4 ev;
#pragma unroll
      for (int jj = 0; jj < 4; ++jj) ev[jj] = __shfl(esc, l4 * 4 + jj);
#pragma unroll
      for (int n = 0; n < 16; ++n) acc[n] *= ev;
      lrun = lrun * esc + psum;
      mrun = mnew;
    }
#pragma unroll
    for (int mp = 0; mp < 2; ++mp)
#pragma unroll
      for (int j2 = 0; j2 < 2; ++j2) {
        unsigned lo = f2bf(pex[mp * 4 + j2 * 2]);
        unsigned hi = f2bf(pex[mp * 4 + j2 * 2 + 1]);
        *(unsigned*)&Plds[w][l15 * 40 + mp * 16 + l4 * 4 + j2 * 2] = lo | (hi << 16);
      }
    asm volatile("s_waitcnt lgkmcnt(0)" ::: "memory");
    __builtin_amdgcn_sched_barrier(0);
    bf16x8 pa = *(const bf16x8*)&Plds[w][l15 * 40 + l4 * 8];
    const char* Vc = (const char*)&Vs[buf][0] + lofs;
    __builtin_amdgcn_s_setprio(1);
#pragma unroll
    for (int n = 0; n < 16; ++n) {
      bf16x8 vb = *(const bf16x8*)(Vc + n * 1024);
      acc[n] = __builtin_amdgcn_mfma_f32_16x16x32_bf16(pa, vb, acc[n], 0, 0, 0);
    }
    __builtin_amdgcn_s_setprio(0);
  };

  int cur = 0;
  stage(0);
  for (int k0 = kstart; k0 < kend - 32; k0 += 32) {
    stage(cur ^ 1);
    asm volatile("s_waitcnt vmcnt(8)" ::: "memory");
    __builtin_amdgcn_s_barrier();
    __builtin_amdgcn_sched_barrier(0);
    compute(cur, k0);
    __builtin_amdgcn_s_barrier();
    cur ^= 1;
  }
  asm volatile("s_waitcnt vmcnt(0)" ::: "memory");
  __builtin_amdgcn_s_barrier();
  __builtin_amdgcn_sched_barrier(0);
  compute(cur, kend - 32);

  f32x4 linv;
#pragma unroll
  for (int jj = 0; jj < 4; ++jj) linv[jj] = 1.0f / __shfl(lrun, l4 * 4 + jj);
#pragma unroll
  for (int jj = 0; jj < 4; ++jj) {
    int row = s0 + w * 16 + l4 * 4 + jj;
    U16* op = O + ((long)b * 2048 + row) * 4096 + h * 256 + l15;
#pragma unroll
    for (int n = 0; n < 16; ++n) op[n * 16] = f2bf(acc[n][jj] * linv[jj]);
  }
}

// ----------------------------------------------------------------------------
extern "C" void kernel_launch(void* const* d_in, const int* in_sizes, int n_in,
                              void* d_out, int out_size, void* d_ws, size_t ws_size,
                              hipStream_t stream) {
  if (n_in < 5) return;
  const float* hid = (const float*)d_in[0];
  const float* Wq  = (const float*)d_in[1];
  const float* Wk  = (const float*)d_in[2];
  const float* Wv  = (const float*)d_in[3];
  const float* Wo  = (const float*)d_in[4];

  char* ws = (char*)d_ws;
  size_t off = 0;
  auto alloc = [&](size_t bytes) {
    char* p = ws + off;
    off += (bytes + 255) & ~(size_t)255;
    return p;
  };
  float* cosT = (float*)alloc((size_t)2048 * 128 * 4);
  float* sinT = (float*)alloc((size_t)2048 * 128 * 4);
  U16*   Xb   = (U16*)alloc((size_t)4096 * 3584 * 2);   // reused: VT, then Wot
  U16*   Wt   = (U16*)alloc((size_t)8192 * 3584 * 2);   // reused: AttO
  U16*   QKV  = (U16*)alloc((size_t)4096 * 8192 * 2);
  if (off > ws_size) return;
  U16* VT   = Xb;
  U16* Wot  = Xb;
  U16* AttO = Wt;

  k_convert<<<7168, 256, 0, stream>>>(hid, Xb, (long)4096 * 3584);
  k_transpose<<<dim3(32, 112), 256, 0, stream>>>(Wq, Wt, 3584, 4096);
  k_transpose<<<dim3(16, 112), 256, 0, stream>>>(Wk, Wt + (size_t)4096 * 3584, 3584, 2048);
  k_transpose<<<dim3(16, 112), 256, 0, stream>>>(Wv, Wt + (size_t)6144 * 3584, 3584, 2048);
  k_rope_tables<<<1024, 256, 0, stream>>>(cosT, sinT);
  k_gemm8<0><<<dim3(32, 16), 512, 0, stream>>>(Xb, Wt, QKV, cosT, sinT, 4096, 8192, 3584);
  k_vtrans<<<dim3(64, 1, 16), 256, 0, stream>>>(QKV, VT);
  k_attn<<<dim3(32, 16, 2), 256, 0, stream>>>(QKV, VT, AttO);
  k_transpose<<<dim3(28, 128), 256, 0, stream>>>(Wo, Wot, 4096, 3584);
  k_gemm8<1><<<dim3(14, 16), 512, 0, stream>>>(AttO, Wot, d_out, cosT, sinT, 4096, 3584, 4096);
}

// Round 19
// 607.446 us; speedup vs baseline: 1.2273x; 1.0204x over previous
//
#include <hip/hip_runtime.h>
#include <stdint.h>

typedef unsigned short U16;
typedef float f32x4 __attribute__((ext_vector_type(4)));
typedef __bf16 bf16x8 __attribute__((ext_vector_type(8)));

static __device__ __forceinline__ U16 f2bf(float x) {
  union { float f; unsigned u; } v; v.f = x;
  unsigned r = v.u + 0x7FFFu + ((v.u >> 16) & 1u);
  return (U16)(r >> 16);
}
static __device__ __forceinline__ float bf2f(U16 h) {
  union { unsigned u; float f; } v; v.u = ((unsigned)h) << 16;
  return v.f;
}

static __device__ __forceinline__ void gload_lds16(const void* g, void* l) {
  __builtin_amdgcn_global_load_lds(
      (const __attribute__((address_space(1))) void*)g,
      (__attribute__((address_space(3))) void*)l, 16, 0, 0);
}

#define SBAR() __builtin_amdgcn_sched_barrier(0)

// ---------------- hidden (fp32) -> bf16 -------------------------------------
__global__ __launch_bounds__(256) void k_convert(const float* __restrict__ src,
                                                 U16* __restrict__ dst, long n) {
  long base = ((long)blockIdx.x * 256 + threadIdx.x) * 8;
  if (base >= n) return;
  const float4* s = (const float4*)(src + base);
  float4 a = s[0], b = s[1];
  U16 o[8] = { f2bf(a.x), f2bf(a.y), f2bf(a.z), f2bf(a.w),
               f2bf(b.x), f2bf(b.y), f2bf(b.z), f2bf(b.w) };
  *(uint4*)(dst + base) = *(const uint4*)o;
}

// ------- W[K][N] (fp32) -> Wt[N][K] bf16, vectorized (32k x 128n tiles) -----
__global__ __launch_bounds__(256) void k_transpose(const float* __restrict__ src,
                                                   U16* __restrict__ dst,
                                                   int K, int N) {
  __shared__ U16 tile[32][132];
  int n0 = blockIdx.x * 128, k0 = blockIdx.y * 32;
  int t = threadIdx.x;
  int tx = t & 31, ty = t >> 5;
#pragma unroll
  for (int r = 0; r < 4; ++r) {
    int k = ty + r * 8;
    float4 v = *(const float4*)(src + (long)(k0 + k) * N + n0 + tx * 4);
    U16* tp = &tile[k][tx * 4];
    tp[0] = f2bf(v.x); tp[1] = f2bf(v.y); tp[2] = f2bf(v.z); tp[3] = f2bf(v.w);
  }
  __syncthreads();
  int k8 = (t & 3) * 8;
#pragma unroll
  for (int r = 0; r < 2; ++r) {
    int n = r * 64 + (t >> 2);
    U16 o[8];
#pragma unroll
    for (int i = 0; i < 8; ++i) o[i] = tile[k8 + i][n];
    *(uint4*)(dst + (long)(n0 + n) * K + k0 + k8) = *(const uint4*)o;
  }
}

// ---- V section of QKV -> VT tiled [bk][sTile=64][d=256][s32=32], vectorized -
__global__ __launch_bounds__(256) void k_vtrans(const U16* __restrict__ QKV,
                                                U16* __restrict__ VT) {
  __shared__ U16 tile[32][264];
  int s0 = blockIdx.x * 32, bk = blockIdx.z;
  int b = bk >> 3, kvh = bk & 7;
  int t = threadIdx.x;
  const U16* src = QKV + (long)(b * 2048) * 8192 + 6144 + kvh * 256;
  int tx = t & 31, ty = t >> 5;
#pragma unroll
  for (int r = 0; r < 4; ++r) {
    int s = ty + r * 8;
    *(uint4*)&tile[s][tx * 8] = *(const uint4*)(src + (long)(s0 + s) * 8192 + tx * 8);
  }
  __syncthreads();
  long tbase = ((long)bk * 64 + (s0 >> 5)) * 8192;
  int s8 = (t & 3) * 8;
#pragma unroll
  for (int r = 0; r < 4; ++r) {
    int d = r * 64 + (t >> 2);
    U16 o[8];
#pragma unroll
    for (int i = 0; i < 8; ++i) o[i] = tile[s8 + i][d];
    *(uint4*)(VT + tbase + d * 32 + s8) = *(const uint4*)o;
  }
}

// ---------------- RoPE tables (fp32) ----------------------------------------
__global__ __launch_bounds__(256) void k_rope_tables(float* __restrict__ cosT,
                                                     float* __restrict__ sinT) {
  int i = blockIdx.x * 256 + threadIdx.x;
  int s = i >> 7, d = i & 127;
  float freq = expf(-9.210340371976184f * (float)d / 128.0f);
  float ang = (float)s * freq;
  cosT[i] = cosf(ang);
  sinT[i] = sinf(ang);
}

// ---------------- GEMM v10: 256x256, BK=64, minimal-barrier schedule --------
// Per tile (buf=b&1): quads (0,0),(0,1) run with NO barrier (reads certified
// per-wave by MFMA data deps); BARRIER-1 then stage B-h0(b+2) (all waves'
// B-h0(b) reads certified complete by their MFMA(0,0) consumption); readA1;
// MFMA(1,1); BARRIER-2 then stage A-h0(b+2) (readA1 certified by MFMA(1,1));
// MFMA(1,0); vmcnt(4)+barrier per tile end (tile b+1 resident). b+1 stages
// target the other buffer (no sync needed). 6 barriers/iter vs 10.
// Accumulation order unchanged -> bitwise-identical output.
template <int EPI>
__global__ __launch_bounds__(512, 1) void k_gemm8(const U16* __restrict__ A,
                                                  const U16* __restrict__ Bt,
                                                  void* __restrict__ Cv,
                                                  const float* __restrict__ cosT,
                                                  const float* __restrict__ sinT,
                                                  int M, int N, int K) {
  __shared__ __align__(16) U16 Asl[2][2][128 * 64];
  __shared__ __align__(16) U16 Bsl[2][2][128 * 64];
  int nwg = gridDim.x * gridDim.y;
  int flat = blockIdx.y * gridDim.x + blockIdx.x;
  int cpx = nwg >> 3;
  int swz = (flat & 7) * cpx + (flat >> 3);
  int bx = swz % gridDim.x, by = swz / gridDim.x;
  int t = threadIdx.x, lane = t & 63, w = t >> 6;
  int m0 = by * 256, n0 = bx * 256;
  int wm = w >> 2, wn = w & 3;
  int l15 = lane & 15, l4 = lane >> 4;
  int lofs = ((lane & 15) * 4 + ((lane >> 4) ^ ((lane >> 1) & 3))) * 16;

  f32x4 acc[8][4] = {};
  int T = K >> 6;

  int sr = lane >> 2, sc4 = ((lane & 3) ^ ((lane >> 3) & 3)) * 8;
  int fA0 = (w >> 1) * 16 + sr, kA0 = (w & 1) * 32 + sc4;
  int fA1 = ((8 + w) >> 1) * 16 + sr, kA1 = ((8 + w) & 1) * 32 + sc4;
  const U16* aj0 = A + (long)(m0 + fA0) * K + kA0;
  const U16* aj1 = A + (long)(m0 + fA1) * K + kA1;
  const U16* bj0 = Bt + (long)(n0 + fA0) * K + kA0;
  const U16* bj1 = Bt + (long)(n0 + fA1) * K + kA1;

  auto stageH = [&](int op, int kt, int h) {
    int buf = kt & 1;
    int ktc = (kt < T) ? kt : 0;
    long off = (long)ktc * 64 + (long)h * 128 * K;
    if (op == 0) {
      gload_lds16(aj0 + off, (char*)&Asl[buf][h][0] + w * 1024);
      gload_lds16(aj1 + off, (char*)&Asl[buf][h][0] + 8192 + w * 1024);
    } else {
      gload_lds16(bj0 + off, (char*)&Bsl[buf][h][0] + w * 1024);
      gload_lds16(bj1 + off, (char*)&Bsl[buf][h][0] + 8192 + w * 1024);
    }
  };

  bf16x8 Ar[4][2], Bq[2][2][2];

  auto readA = [&](int buf, int r) {
    const char* base = (const char*)&Asl[buf][wm][0] + lofs;
#pragma unroll
    for (int i = 0; i < 4; ++i)
#pragma unroll
      for (int kk = 0; kk < 2; ++kk)
        Ar[i][kk] = *(const bf16x8*)(base + ((r * 4 + i) * 2 + kk) * 1024);
  };
  auto readB = [&](int buf, int c) {
    const char* base = (const char*)&Bsl[buf][c][0] + lofs;
#pragma unroll
    for (int j = 0; j < 2; ++j)
#pragma unroll
      for (int kk = 0; kk < 2; ++kk)
        Bq[c][j][kk] = *(const bf16x8*)(base + ((2 * wn + j) * 2 + kk) * 1024);
  };
  auto mfmaQ = [&](int r, int c) {
    __builtin_amdgcn_s_setprio(1);
#pragma unroll
    for (int i = 0; i < 4; ++i)
#pragma unroll
      for (int j = 0; j < 2; ++j) {
        int m = r * 4 + i, n = c * 2 + j;
        acc[m][n] = __builtin_amdgcn_mfma_f32_16x16x32_bf16(Ar[i][0], Bq[c][j][0], acc[m][n], 0, 0, 0);
        acc[m][n] = __builtin_amdgcn_mfma_f32_16x16x32_bf16(Ar[i][1], Bq[c][j][1], acc[m][n], 0, 0, 0);
      }
    __builtin_amdgcn_s_setprio(0);
  };

#define BARR() do { SBAR(); __builtin_amdgcn_s_barrier(); SBAR(); } while (0)

  // prologue: tile0 all 4 halves, tile1 Bh0+Ah0; vmcnt(4); barrier
  stageH(0, 0, 0); stageH(0, 0, 1); stageH(1, 0, 0); stageH(1, 0, 1);
  stageH(1, 1, 0); stageH(0, 1, 0);
  asm volatile("s_waitcnt vmcnt(4)" ::: "memory");
  BARR();

  for (int base = 0; base < T; base += 2) {
#pragma unroll
    for (int half = 0; half < 2; ++half) {
      int b = base + half;
      int buf = b & 1;
      // --- free-flow stretch: quads (0,0),(0,1); b+1 stages (other buf) ---
      readA(buf, 0); readB(buf, 0);
      stageH(0, b + 1, 1);
      mfmaQ(0, 0);
      readB(buf, 1);
      stageH(1, b + 1, 1);
      mfmaQ(0, 1);
      // --- BARRIER-1: all waves' B-h0(b) reads done (consumed by MFMA) ---
      BARR();
      stageH(1, b + 2, 0);            // B-h0(b+2) safe
      readA(buf, 1);
      mfmaQ(1, 1);
      // --- BARRIER-2: all waves' A reads done (consumed by MFMA(1,1)) ---
      BARR();
      stageH(0, b + 2, 0);            // A-h0(b+2) safe
      mfmaQ(1, 0);                    // register reuse, no reads
      // --- tile end: certify tile b+1 resident ---
      asm volatile("s_waitcnt vmcnt(4)" ::: "memory");
      BARR();
    }
  }

#undef BARR

  bool doRope = (EPI == 0) && (n0 < 6144);
#pragma unroll
  for (int m = 0; m < 8; ++m)
#pragma unroll
    for (int jj = 0; jj < 4; ++jj) {
      int row = m0 + wm * 128 + m * 16 + l4 * 4 + jj;
      int s2 = row & 2047;
#pragma unroll
      for (int j = 0; j < 2; ++j) {
        float lo = acc[m][j][jj];
        float hi = acc[m][2 + j][jj];
        int cl = wn * 32 + j * 16 + l15;
        if (EPI == 0) {
          if (doRope) {
            int d = cl;
            float co = cosT[s2 * 128 + d];
            float si = sinT[s2 * 128 + d];
            float o0 = lo * co - hi * si;
            float o1 = hi * co + lo * si;
            lo = o0; hi = o1;
          }
          U16* cp = (U16*)Cv + (long)row * N + n0 + cl;
          cp[0] = f2bf(lo);
          cp[128] = f2bf(hi);
        } else {
          float* cp = (float*)Cv + (long)row * N + n0 + cl;
          cp[0] = lo;
          cp[128] = hi;
        }
      }
    }
}

// ---------------- banded GQA attention (v9, r16 unchanged) ------------------
__global__ __launch_bounds__(256) void k_attn(const U16* __restrict__ QKV,
                                              const U16* __restrict__ VT,
                                              U16* __restrict__ O) {
  __shared__ __align__(16) U16 Ks[2][32 * 256];
  __shared__ __align__(16) U16 Vs[2][256 * 32];
  __shared__ __align__(16) U16 Plds[4][16 * 40];
  int t = threadIdx.x, lane = t & 63, w = t >> 6;
  int flat = blockIdx.x + 32 * (blockIdx.y + 16 * blockIdx.z);
  int l = (flat & 7) * 128 + (flat >> 3);
  int qb = l & 31, h = (l >> 5) & 15, b = l >> 9;
  int s0 = qb * 64;
  int kvh = h >> 1;
  long rowOff = (long)b * 2048 * 8192;
  const U16* Qb = QKV + rowOff + h * 256;
  const U16* Kb = QKV + rowOff + 4096 + kvh * 256;
  const U16* VTb = VT + (long)(b * 8 + kvh) * 64 * 8192;

  int l15 = lane & 15, l4 = lane >> 4;
  int lofs = ((lane & 15) * 4 + ((lane >> 4) ^ ((lane >> 1) & 3))) * 16;

  bf16x8 qf[8];
  {
    const U16* qp = Qb + (long)(s0 + w * 16 + l15) * 8192 + l4 * 8;
#pragma unroll
    for (int kc = 0; kc < 8; ++kc) qf[kc] = *(const bf16x8*)(qp + kc * 32);
  }
  asm volatile("s_waitcnt vmcnt(0)" ::: "memory");

  f32x4 acc[16] = {};
  float mrun = -1e30f, lrun = 0.0f;
  int qpos = s0 + w * 16 + l15;
  int qlo = s0 + w * 16, qhi = qlo + 15;

  int kstart = s0 - 1024; if (kstart < 0) kstart = 0;
  int kend = s0 + 64 + 1024; if (kend > 2048) kend = 2048;

  int sl15 = (t >> 2) & 15, sl4x = (t & 3) ^ ((t >> 3) & 3);
  int offK[4], offV[4];
#pragma unroll
  for (int i = 0; i < 4; ++i) {
    int f = i * 4 + w;
    offK[i] = ((f >> 3) * 16 + sl15) * 8192 + (f & 7) * 32 + sl4x * 8;
    offV[i] = (f * 16 + sl15) * 32 + sl4x * 8;
  }

  const U16* kb = Kb + (long)kstart * 8192;
  const U16* vt0 = VTb + (long)(kstart >> 5) * 8192;

  auto stage = [&](int buf) {
#pragma unroll
    for (int i = 0; i < 4; ++i)
      gload_lds16(kb + offK[i], (char*)&Ks[buf][0] + i * 4096 + w * 1024);
#pragma unroll
    for (int i = 0; i < 4; ++i)
      gload_lds16(vt0 + offV[i], (char*)&Vs[buf][0] + i * 4096 + w * 1024);
    kb += (long)32 * 8192;
    vt0 += 8192;
  };

  auto compute = [&](int buf, int k0) {
    f32x4 sAcc[2] = {};
    const char* Kc = (const char*)&Ks[buf][0] + lofs;
    __builtin_amdgcn_s_setprio(1);
#pragma unroll
    for (int kc = 0; kc < 8; ++kc) {
      bf16x8 a0 = *(const bf16x8*)(Kc + kc * 1024);
      bf16x8 a1 = *(const bf16x8*)(Kc + (8 + kc) * 1024);
      sAcc[0] = __builtin_amdgcn_mfma_f32_16x16x32_bf16(a0, qf[kc], sAcc[0], 0, 0, 0);
      sAcc[1] = __builtin_amdgcn_mfma_f32_16x16x32_bf16(a1, qf[kc], sAcc[1], 0, 0, 0);
    }
    __builtin_amdgcn_s_setprio(0);
    float sv[8];
#pragma unroll
    for (int mp = 0; mp < 2; ++mp)
#pragma unroll
      for (int jj = 0; jj < 4; ++jj) {
        float ex = __expf(sAcc[mp][jj] * 0.0025f);
        sv[mp * 4 + jj] = fmaf(-100.0f, __builtin_amdgcn_rcpf(ex + 1.0f), 50.0f);
      }
    bool full = ((qhi - k0) <= 1024) && ((k0 + 31 - qlo) <= 1024);
    if (!full) {
#pragma unroll
      for (int mp = 0; mp < 2; ++mp)
#pragma unroll
        for (int jj = 0; jj < 4; ++jj) {
          int key = k0 + mp * 16 + l4 * 4 + jj;
          int dd = qpos - key;
          if (dd < -1024 || dd > 1024) sv[mp * 4 + jj] = -3e38f;
        }
    }
    float tmax = sv[0];
#pragma unroll
    for (int i = 1; i < 8; ++i) tmax = fmaxf(tmax, sv[i]);
    tmax = fmaxf(tmax, __shfl_xor(tmax, 16));
    tmax = fmaxf(tmax, __shfl_xor(tmax, 32));
    bool skipall = __all((tmax <= mrun + 8.0f) ? 1 : 0) != 0;
    float mnew = skipall ? mrun : fmaxf(mrun, tmax);
    float pex[8];
    float psum = 0.0f;
#pragma unroll
    for (int i = 0; i < 8; ++i) { pex[i] = __expf(sv[i] - mnew); psum += pex[i]; }
    psum += __shfl_xor(psum, 16);
    psum += __shfl_xor(psum, 32);
    if (skipall) {
      lrun += psum;
    } else {
      float esc = __expf(mrun - mnew);
      f32x4 ev;
#pragma unroll
      for (int jj = 0; jj < 4; ++jj) ev[jj] = __shfl(esc, l4 * 4 + jj);
#pragma unroll
      for (int n = 0; n < 16; ++n) acc[n] *= ev;
      lrun = lrun * esc + psum;
      mrun = mnew;
    }
#pragma unroll
    for (int mp = 0; mp < 2; ++mp)
#pragma unroll
      for (int j2 = 0; j2 < 2; ++j2) {
        unsigned lo = f2bf(pex[mp * 4 + j2 * 2]);
        unsigned hi = f2bf(pex[mp * 4 + j2 * 2 + 1]);
        *(unsigned*)&Plds[w][l15 * 40 + mp * 16 + l4 * 4 + j2 * 2] = lo | (hi << 16);
      }
    asm volatile("s_waitcnt lgkmcnt(0)" ::: "memory");
    __builtin_amdgcn_sched_barrier(0);
    bf16x8 pa = *(const bf16x8*)&Plds[w][l15 * 40 + l4 * 8];
    const char* Vc = (const char*)&Vs[buf][0] + lofs;
    __builtin_amdgcn_s_setprio(1);
#pragma unroll
    for (int n = 0; n < 16; ++n) {
      bf16x8 vb = *(const bf16x8*)(Vc + n * 1024);
      acc[n] = __builtin_amdgcn_mfma_f32_16x16x32_bf16(pa, vb, acc[n], 0, 0, 0);
    }
    __builtin_amdgcn_s_setprio(0);
  };

  int cur = 0;
  stage(0);
  for (int k0 = kstart; k0 < kend - 32; k0 += 32) {
    stage(cur ^ 1);
    asm volatile("s_waitcnt vmcnt(8)" ::: "memory");
    __builtin_amdgcn_s_barrier();
    __builtin_amdgcn_sched_barrier(0);
    compute(cur, k0);
    __builtin_amdgcn_s_barrier();
    cur ^= 1;
  }
  asm volatile("s_waitcnt vmcnt(0)" ::: "memory");
  __builtin_amdgcn_s_barrier();
  __builtin_amdgcn_sched_barrier(0);
  compute(cur, kend - 32);

  f32x4 linv;
#pragma unroll
  for (int jj = 0; jj < 4; ++jj) linv[jj] = 1.0f / __shfl(lrun, l4 * 4 + jj);
#pragma unroll
  for (int jj = 0; jj < 4; ++jj) {
    int row = s0 + w * 16 + l4 * 4 + jj;
    U16* op = O + ((long)b * 2048 + row) * 4096 + h * 256 + l15;
#pragma unroll
    for (int n = 0; n < 16; ++n) op[n * 16] = f2bf(acc[n][jj] * linv[jj]);
  }
}

// ----------------------------------------------------------------------------
extern "C" void kernel_launch(void* const* d_in, const int* in_sizes, int n_in,
                              void* d_out, int out_size, void* d_ws, size_t ws_size,
                              hipStream_t stream) {
  if (n_in < 5) return;
  const float* hid = (const float*)d_in[0];
  const float* Wq  = (const float*)d_in[1];
  const float* Wk  = (const float*)d_in[2];
  const float* Wv  = (const float*)d_in[3];
  const float* Wo  = (const float*)d_in[4];

  char* ws = (char*)d_ws;
  size_t off = 0;
  auto alloc = [&](size_t bytes) {
    char* p = ws + off;
    off += (bytes + 255) & ~(size_t)255;
    return p;
  };
  float* cosT = (float*)alloc((size_t)2048 * 128 * 4);
  float* sinT = (float*)alloc((size_t)2048 * 128 * 4);
  U16*   Xb   = (U16*)alloc((size_t)4096 * 3584 * 2);   // reused: VT, then Wot
  U16*   Wt   = (U16*)alloc((size_t)8192 * 3584 * 2);   // reused: AttO
  U16*   QKV  = (U16*)alloc((size_t)4096 * 8192 * 2);
  if (off > ws_size) return;
  U16* VT   = Xb;
  U16* Wot  = Xb;
  U16* AttO = Wt;

  k_convert<<<7168, 256, 0, stream>>>(hid, Xb, (long)4096 * 3584);
  k_transpose<<<dim3(32, 112), 256, 0, stream>>>(Wq, Wt, 3584, 4096);
  k_transpose<<<dim3(16, 112), 256, 0, stream>>>(Wk, Wt + (size_t)4096 * 3584, 3584, 2048);
  k_transpose<<<dim3(16, 112), 256, 0, stream>>>(Wv, Wt + (size_t)6144 * 3584, 3584, 2048);
  k_rope_tables<<<1024, 256, 0, stream>>>(cosT, sinT);
  k_gemm8<0><<<dim3(32, 16), 512, 0, stream>>>(Xb, Wt, QKV, cosT, sinT, 4096, 8192, 3584);
  k_vtrans<<<dim3(64, 1, 16), 256, 0, stream>>>(QKV, VT);
  k_attn<<<dim3(32, 16, 2), 256, 0, stream>>>(QKV, VT, AttO);
  k_transpose<<<dim3(28, 128), 256, 0, stream>>>(Wo, Wot, 4096, 3584);
  k_gemm8<1><<<dim3(14, 16), 512, 0, stream>>>(AttO, Wot, d_out, cosT, sinT, 4096, 3584, 4096);
}